// Round 10
// baseline (495.360 us; speedup 1.0000x reference)
//
#include <hip/hip_runtime.h>
#include <math.h>

namespace {

constexpr int Bc = 4, Tc = 1024, Cch = 768, Hc = 12, Dc = 64, KSEL = 10;
constexpr size_t BTC    = (size_t)Bc * Tc * Cch;        // 3,145,728
constexpr size_t PROBSN = (size_t)Bc * Hc * Tc * Tc;    // 50,331,648
constexpr size_t CC     = (size_t)Cch * Cch;            // 589,824

typedef __attribute__((ext_vector_type(8))) short          bf16x8;
typedef __attribute__((ext_vector_type(4))) float          f32x4;
typedef __attribute__((ext_vector_type(4))) unsigned short u16x4;
typedef __attribute__((ext_vector_type(8))) unsigned short u16x8;

// round-to-nearest-even f32 -> bf16 (raw bits); finite inputs only
__device__ __forceinline__ unsigned short bf16rne(float x) {
  unsigned int u = __float_as_uint(x);
  return (unsigned short)((u + 0x7FFFu + ((u >> 16) & 1u)) >> 16);
}
__device__ __forceinline__ float bf16tof(unsigned short h) {
  return __uint_as_float(((unsigned int)h) << 16);
}

// ---------------------------------------------------------------------------
// split_plane: f32[n] -> bf16 hi/lo planes.  n multiple of 1024.
// ---------------------------------------------------------------------------
__global__ __launch_bounds__(256) void split_plane(
    const float* __restrict__ src,
    unsigned short* __restrict__ h, unsigned short* __restrict__ l)
{
  const size_t i = (size_t)(blockIdx.x * 256 + threadIdx.x) * 4;
  const float4 v = *(const float4*)&src[i];
  const float xs[4] = {v.x, v.y, v.z, v.w};
  u16x4 hh, ll;
  #pragma unroll
  for (int e = 0; e < 4; ++e) {
    const unsigned short hb = bf16rne(xs[e]);
    hh[e] = hb;
    ll[e] = bf16rne(xs[e] - bf16tof(hb));
  }
  *(u16x4*)&h[i] = hh;
  *(u16x4*)&l[i] = ll;
}

// ---------------------------------------------------------------------------
// splitT_w: W[k][n] (768x768 f32) -> transposed bf16 planes th/tl [n][k].
// ---------------------------------------------------------------------------
__global__ __launch_bounds__(256) void splitT_w(
    const float* __restrict__ W,
    unsigned short* __restrict__ th, unsigned short* __restrict__ tl)
{
  __shared__ float tile[32][33];
  const int n0 = blockIdx.x * 32, k0 = blockIdx.y * 32;
  const int x = threadIdx.x & 31, y = threadIdx.x >> 5;   // y 0..7

  #pragma unroll
  for (int i = 0; i < 4; ++i) {
    const int kk = y * 4 + i;
    tile[kk][x] = W[(size_t)(k0 + kk) * Cch + n0 + x];
  }
  __syncthreads();
  #pragma unroll
  for (int i = 0; i < 4; ++i) {
    const int nn = y * 4 + i;
    const float v = tile[x][nn];                          // = W[k0+x][n0+nn]
    const unsigned short hb = bf16rne(v);
    th[(size_t)(n0 + nn) * Cch + k0 + x] = hb;
    tl[(size_t)(n0 + nn) * Cch + k0 + x] = bf16rne(v - bf16tof(hb));
  }
}

// ---------------------------------------------------------------------------
// qkv_mfma: [Q|K|V] = hid @ W + b, split-bf16 MFMA.  (unchanged)
// ---------------------------------------------------------------------------
__global__ __launch_bounds__(256) void qkv_mfma(
    const unsigned short* __restrict__ hidh, const unsigned short* __restrict__ hidl,
    const unsigned short* __restrict__ wqth, const unsigned short* __restrict__ wqtl,
    const unsigned short* __restrict__ wkth, const unsigned short* __restrict__ wktl,
    const unsigned short* __restrict__ wvth, const unsigned short* __restrict__ wvtl,
    const float* __restrict__ bq, const float* __restrict__ bk,
    const float* __restrict__ bv,
    unsigned short* __restrict__ qh, unsigned short* __restrict__ ql,
    unsigned short* __restrict__ kh, unsigned short* __restrict__ kl,
    float* __restrict__ V)
{
  const int z = blockIdx.z;
  const unsigned short* __restrict__ Bhp = (z == 0) ? wqth : (z == 1) ? wkth : wvth;
  const unsigned short* __restrict__ Blp = (z == 0) ? wqtl : (z == 1) ? wktl : wvtl;
  const float* __restrict__ bias = (z == 0) ? bq : (z == 1) ? bk : bv;

  const int m0 = blockIdx.y * 64;
  const int n0 = blockIdx.x * 128;

  __shared__ unsigned short Ah[64][72],  Al[64][72];
  __shared__ unsigned short Bh[128][72], Bl[128][72];

  const int t    = threadIdx.x;
  const int lane = t & 63;
  const int wv   = t >> 6;
  const int wq   = (wv >> 1) * 32;
  const int wk   = (wv & 1) * 64;
  const int fr   = lane & 15;
  const int fg   = lane >> 4;

  f32x4 acc[2][4] = {};

  for (int k0 = 0; k0 < Cch; k0 += 64) {
    __syncthreads();
    #pragma unroll
    for (int i = 0; i < 2; ++i) {       // A: 64x64 x 2 planes
      const int id = t + 256*i;
      const int r = id >> 3, c8 = (id & 7) * 8;
      *(u16x8*)&Ah[r][c8] = *(const u16x8*)&hidh[(size_t)(m0 + r)*Cch + k0 + c8];
      *(u16x8*)&Al[r][c8] = *(const u16x8*)&hidl[(size_t)(m0 + r)*Cch + k0 + c8];
    }
    #pragma unroll
    for (int i = 0; i < 4; ++i) {       // B: 128x64 x 2 planes
      const int id = t + 256*i;
      const int r = id >> 3, c8 = (id & 7) * 8;
      *(u16x8*)&Bh[r][c8] = *(const u16x8*)&Bhp[(size_t)(n0 + r)*Cch + k0 + c8];
      *(u16x8*)&Bl[r][c8] = *(const u16x8*)&Blp[(size_t)(n0 + r)*Cch + k0 + c8];
    }
    __syncthreads();

    #pragma unroll
    for (int g2 = 0; g2 < 2; ++g2) {
      const int dof = g2*32 + 8*fg;
      bf16x8 aH[2], aL[2];
      #pragma unroll
      for (int qt = 0; qt < 2; ++qt) {
        aH[qt] = *(const bf16x8*)&Ah[wq + qt*16 + fr][dof];
        aL[qt] = *(const bf16x8*)&Al[wq + qt*16 + fr][dof];
      }
      #pragma unroll
      for (int kt = 0; kt < 4; ++kt) {
        const bf16x8 bH = *(const bf16x8*)&Bh[wk + kt*16 + fr][dof];
        const bf16x8 bL = *(const bf16x8*)&Bl[wk + kt*16 + fr][dof];
        #pragma unroll
        for (int qt = 0; qt < 2; ++qt) {
          acc[qt][kt] = __builtin_amdgcn_mfma_f32_16x16x32_bf16(
              aH[qt], bH, acc[qt][kt], 0, 0, 0);
          acc[qt][kt] = __builtin_amdgcn_mfma_f32_16x16x32_bf16(
              aH[qt], bL, acc[qt][kt], 0, 0, 0);
          acc[qt][kt] = __builtin_amdgcn_mfma_f32_16x16x32_bf16(
              aL[qt], bH, acc[qt][kt], 0, 0, 0);
        }
      }
    }
  }

  float bcol[4];
  #pragma unroll
  for (int kt = 0; kt < 4; ++kt) bcol[kt] = bias[n0 + wk + kt*16 + fr];

  unsigned short* __restrict__ dh = (z == 0) ? qh : kh;
  unsigned short* __restrict__ dl = (z == 0) ? ql : kl;

  #pragma unroll
  for (int qt = 0; qt < 2; ++qt) {
    #pragma unroll
    for (int j = 0; j < 4; ++j) {
      const int m  = m0 + wq + qt*16 + 4*fg + j;
      const int b  = m >> 10, tt = m & 1023;
      #pragma unroll
      for (int kt = 0; kt < 4; ++kt) {
        const int col = n0 + wk + kt*16 + fr;
        const float val = acc[qt][kt][j] + bcol[kt];
        const size_t idx =
            (((size_t)(b*Hc + (col >> 6)))*Tc + tt)*Dc + (col & 63);
        if (z < 2) {
          const unsigned short hb = bf16rne(val);
          dh[idx] = hb;
          dl[idx] = bf16rne(val - bf16tof(hb));
        } else {
          V[idx] = val;
        }
      }
    }
  }
}

// ---------------------------------------------------------------------------
// score_topk: FUSED scores + softmax + UCB top-k + renorm + count + sparse PV.
// Block = 16 q-rows, 1024 threads (16 waves).  Per 128-col K chunk:
//   waves 0-7  : MFMA  aH*bH + aH*bL  for col strip 16*(wv&7) -> scA
//   waves 8-15 : MFMA  aL*bH                                  -> scB
//   wave wv then reads row wv: s[2j]=scA+scB at col lane, s[2j+1] at 64+lane.
// Fragment/C-D conventions identical to the proven score_mfma.  Top-k body
// is verbatim round 9 (u64 keys, 2-shfl butterfly, LDS winner recovery).
// ---------------------------------------------------------------------------
__global__ __launch_bounds__(1024, 4) void score_topk(
    const unsigned short* __restrict__ qhp, const unsigned short* __restrict__ qlp,
    const unsigned short* __restrict__ khp, const unsigned short* __restrict__ klp,
    const float* __restrict__ qkv,          // f32 ws base (for V)
    const float* __restrict__ count_in,
    const int*   __restrict__ counter_p,
    const int*   __restrict__ ucb_p,
    float* __restrict__ probs,
    float* __restrict__ count_out,
    float* __restrict__ ctx)
{
  const int bh = blockIdx.y;
  const int q0 = blockIdx.x * 16;
  const int b  = bh / Hc, h = bh % Hc;

  __shared__ unsigned short Qh[16][72],  Ql[16][72];
  __shared__ unsigned short Kh[128][72], Kl[128][72];
  __shared__ float scA[16][136], scB[16][136];
  __shared__ float psel[16][KSEL];

  const int t    = threadIdx.x;
  const int lane = t & 63;
  const int wv   = t >> 6;          // 0..15; wave wv owns row q0+wv
  const int fr   = lane & 15;
  const int fg   = lane >> 4;
  const int half = wv >> 3;         // 0: A-terms, 1: B-term
  const int c0   = (wv & 7) * 16;   // col strip within chunk

  {   // stage Q 16x64 x 2 planes
    const size_t qb = ((size_t)bh*Tc + q0) * Dc;
    if (t < 128) {
      const int r = t >> 3, c8 = (t & 7) * 8;
      *(u16x8*)&Qh[r][c8] = *(const u16x8*)&qhp[qb + (size_t)r*Dc + c8];
    } else if (t < 256) {
      const int t2 = t - 128;
      const int r = t2 >> 3, c8 = (t2 & 7) * 8;
      *(u16x8*)&Ql[r][c8] = *(const u16x8*)&qlp[qb + (size_t)r*Dc + c8];
    }
  }

  const int krr = t >> 3, kc8 = (t & 7) * 8;   // staging coords (128 rows)

  float s[16];
  #pragma unroll
  for (int j = 0; j < 8; ++j) {     // fully unrolled: static s[] indices
    __syncthreads();                // prev chunk consumed (and Q staged, j=0)
    {
      const size_t kb = ((size_t)bh*Tc + j*128) * Dc;
      *(u16x8*)&Kh[krr][kc8] = *(const u16x8*)&khp[kb + (size_t)krr*Dc + kc8];
      *(u16x8*)&Kl[krr][kc8] = *(const u16x8*)&klp[kb + (size_t)krr*Dc + kc8];
    }
    __syncthreads();                // K chunk staged
    f32x4 acc = {};
    #pragma unroll
    for (int g2 = 0; g2 < 2; ++g2) {
      const int dof = g2*32 + 8*fg;
      const bf16x8 bH = *(const bf16x8*)&Kh[c0 + fr][dof];
      if (half == 0) {
        const bf16x8 aH = *(const bf16x8*)&Qh[fr][dof];
        const bf16x8 bL = *(const bf16x8*)&Kl[c0 + fr][dof];
        acc = __builtin_amdgcn_mfma_f32_16x16x32_bf16(aH, bH, acc, 0, 0, 0);
        acc = __builtin_amdgcn_mfma_f32_16x16x32_bf16(aH, bL, acc, 0, 0, 0);
      } else {
        const bf16x8 aL = *(const bf16x8*)&Ql[fr][dof];
        acc = __builtin_amdgcn_mfma_f32_16x16x32_bf16(aL, bH, acc, 0, 0, 0);
      }
    }
    if (half == 0) {
      #pragma unroll
      for (int e = 0; e < 4; ++e) scA[4*fg + e][c0 + fr] = acc[e];
    } else {
      #pragma unroll
      for (int e = 0; e < 4; ++e) scB[4*fg + e][c0 + fr] = acc[e];
    }
    __syncthreads();                // scores ready
    s[2*j]     = (scA[wv][lane]      + scB[wv][lane])      * 0.125f;
    s[2*j + 1] = (scA[wv][64 + lane] + scB[wv][64 + lane]) * 0.125f;
  }

  // ---- per-row softmax + UCB top-k (verbatim round-9 body) ----
  const int row = q0 + wv;
  const size_t rb = ((size_t)bh * Tc + row) * Tc;
  const float* __restrict__ Vh = qkv + 2*BTC + (size_t)bh * Tc * Dc;

  const int  counter = counter_p[0];
  const int  ucbf    = ucb_p[0];
  const bool do_ucb  = (ucbf != 0) && (counter >= 1000);
  const float lt     = do_ucb ? logf((float)counter) : 0.f;

  float mx = -INFINITY;
  #pragma unroll
  for (int w = 0; w < 16; ++w) mx = fmaxf(mx, s[w]);
  #pragma unroll
  for (int off = 32; off > 0; off >>= 1) mx = fmaxf(mx, __shfl_xor(mx, off));

  float sum = 0.f;
  #pragma unroll
  for (int w = 0; w < 16; ++w) { s[w] = __expf(s[w] - mx); sum += s[w]; }
  #pragma unroll
  for (int off = 32; off > 0; off >>= 1) sum += __shfl_xor(sum, off);

  const float rsum = 1.0f / sum;
  #pragma unroll
  for (int w = 0; w < 16; ++w) s[w] = s[w] * rsum;     // att

  if (do_ucb) {
    const float sqlt = sqrtf(lt);

    unsigned long long key[16];
    #pragma unroll
    for (int w = 0; w < 16; ++w) {
      const float c = count_in[rb + lane + 64*w];
      count_out[rb + lane + 64*w] = c;
      const float u = fmaf(sqlt, rsqrtf(c + 1e-8f), s[w]);
      key[w] = ((unsigned long long)__float_as_uint(u) << 32)
             | (unsigned long long)(~(unsigned)(lane + (w << 6)));
    }

    unsigned selmask = 0u;
    unsigned long long rpack = 0ull;   // 4-bit round id per w slot
    int ks[KSEL];

    #pragma unroll
    for (int r = 0; r < KSEL; ++r) {
      unsigned long long m = 0ull;
      #pragma unroll
      for (int w = 0; w < 16; ++w) {
        const unsigned long long kw =
            ((selmask >> w) & 1u) ? 0ull : key[w];
        m = (kw > m) ? kw : m;
      }
      #pragma unroll
      for (int off = 32; off > 0; off >>= 1) {
        const unsigned long long o = __shfl_xor(m, off);
        m = (o > m) ? o : m;
      }
      const int idx = (int)(~(unsigned)(m & 0xFFFFFFFFull));
      ks[r] = __builtin_amdgcn_readfirstlane(idx);
      if ((idx & 63) == lane) {
        const int wsel = idx >> 6;
        selmask |= (1u << wsel);
        rpack   |= ((unsigned long long)r << (wsel * 4));
      }
    }

    #pragma unroll
    for (int w = 0; w < 16; ++w) {
      if ((selmask >> w) & 1u) {
        const int r = (int)((rpack >> (4 * w)) & 15ull);
        psel[wv][r] = s[w];
      }
    }
    __syncthreads();    // do_ucb is grid-uniform; all waves reach this

    float pvv[KSEL];
    float denom = 1e-8f;
    #pragma unroll
    for (int r = 0; r < KSEL; ++r) { pvv[r] = psel[wv][r]; denom += pvv[r]; }
    const float rden = 1.0f / denom;

    #pragma unroll
    for (int w = 0; w < 16; ++w) {
      const bool sb = (selmask >> w) & 1u;
      probs[rb + lane + 64*w] = sb ? (s[w] * rden) : 0.0f;
    }
    #pragma unroll
    for (int r = 0; r < KSEL; ++r) {
      if ((ks[r] & 63) == lane)
        count_out[rb + ks[r]] = count_in[rb + ks[r]] + 1.0f;
    }

    float cd = 0.f;
    #pragma unroll
    for (int r = 0; r < KSEL; ++r)
      cd += pvv[r] * Vh[(size_t)ks[r] * Dc + lane];
    ctx[((size_t)b*Tc + row)*Cch + h*Dc + lane] = cd * rden;
  } else {
    #pragma unroll
    for (int w = 0; w < 16; ++w) {
      probs[rb + lane + 64*w]     = s[w];
      count_out[rb + lane + 64*w] = count_in[rb + lane + 64*w];
    }
  }
}

// ---------------------------------------------------------------------------
// K3 (fallback only, non-UCB path): ctx = probs @ V per (b,h).
// ---------------------------------------------------------------------------
__global__ __launch_bounds__(256) void pv_gemm(
    const float* __restrict__ probs,
    const float* __restrict__ Vm,
    float* __restrict__ ctx,
    const int* __restrict__ counter_p,
    const int* __restrict__ ucb_p)
{
  if ((ucb_p[0] != 0) && (counter_p[0] >= 1000)) return;  // fused did sparse PV

  const int bh = blockIdx.y;
  const int q0 = blockIdx.x * 64;
  const int b = bh / Hc, h = bh % Hc;

  __shared__ float aT[32][68];
  __shared__ float vN[32][68];

  const int t  = threadIdx.x;
  const int tn = t & 15;
  const int tq = t >> 4;

  float acc[4][4];
  #pragma unroll
  for (int i = 0; i < 4; ++i)
    #pragma unroll
    for (int j = 0; j < 4; ++j) acc[i][j] = 0.f;

  for (int k0 = 0; k0 < Tc; k0 += 32) {
    __syncthreads();
    #pragma unroll
    for (int p = 0; p < 2; ++p) {
      const int id = t + 256*p;
      const int r = id >> 3, c = id & 7;
      const float4 v =
          *(const float4*)&probs[((size_t)bh*Tc + q0 + r)*Tc + k0 + 4*c];
      aT[4*c + 0][r] = v.x; aT[4*c + 1][r] = v.y;
      aT[4*c + 2][r] = v.z; aT[4*c + 3][r] = v.w;
    }
    #pragma unroll
    for (int p = 0; p < 2; ++p) {
      const int id = t + 256*p;
      const int kk = id >> 4, dcc = id & 15;
      const float4 v = *(const float4*)&Vm[((size_t)bh*Tc + k0 + kk)*Dc + 4*dcc];
      *(float4*)&vN[kk][4*dcc] = v;
    }
    __syncthreads();
    #pragma unroll
    for (int kk = 0; kk < 32; ++kk) {
      const float4 a  = *(const float4*)&aT[kk][4*tq];
      const float4 vv = *(const float4*)&vN[kk][4*tn];
      const float av[4] = {a.x, a.y, a.z, a.w};
      const float bw[4] = {vv.x, vv.y, vv.z, vv.w};
      #pragma unroll
      for (int qi = 0; qi < 4; ++qi)
        #pragma unroll
        for (int ni = 0; ni < 4; ++ni) acc[qi][ni] += av[qi] * bw[ni];
    }
  }

  #pragma unroll
  for (int qi = 0; qi < 4; ++qi) {
    const int tt = q0 + 4*tq + qi;
    float4 o;
    o.x = acc[qi][0]; o.y = acc[qi][1]; o.z = acc[qi][2]; o.w = acc[qi][3];
    *(float4*)&ctx[((size_t)b*Tc + tt)*Cch + h*Dc + 4*tn] = o;
  }
}

// ---------------------------------------------------------------------------
// out_mfma: out = ctx @ Wo + bo, split-bf16 MFMA.  (unchanged)
// ---------------------------------------------------------------------------
__global__ __launch_bounds__(256) void out_mfma(
    const unsigned short* __restrict__ ah, const unsigned short* __restrict__ al,
    const unsigned short* __restrict__ bth, const unsigned short* __restrict__ btl,
    const float* __restrict__ bias,
    float* __restrict__ out)
{
  const int m0 = blockIdx.y * 64;
  const int n0 = blockIdx.x * 128;

  __shared__ unsigned short Ah[64][72],  Al[64][72];
  __shared__ unsigned short Bh[128][72], Bl[128][72];

  const int t    = threadIdx.x;
  const int lane = t & 63;
  const int wv   = t >> 6;
  const int wq   = (wv >> 1) * 32;
  const int wk   = (wv & 1) * 64;
  const int fr   = lane & 15;
  const int fg   = lane >> 4;

  f32x4 acc[2][4] = {};

  for (int k0 = 0; k0 < Cch; k0 += 64) {
    __syncthreads();
    #pragma unroll
    for (int i = 0; i < 2; ++i) {
      const int id = t + 256*i;
      const int r = id >> 3, c8 = (id & 7) * 8;
      *(u16x8*)&Ah[r][c8] = *(const u16x8*)&ah[(size_t)(m0 + r)*Cch + k0 + c8];
      *(u16x8*)&Al[r][c8] = *(const u16x8*)&al[(size_t)(m0 + r)*Cch + k0 + c8];
    }
    #pragma unroll
    for (int i = 0; i < 4; ++i) {
      const int id = t + 256*i;
      const int r = id >> 3, c8 = (id & 7) * 8;
      *(u16x8*)&Bh[r][c8] = *(const u16x8*)&bth[(size_t)(n0 + r)*Cch + k0 + c8];
      *(u16x8*)&Bl[r][c8] = *(const u16x8*)&btl[(size_t)(n0 + r)*Cch + k0 + c8];
    }
    __syncthreads();

    #pragma unroll
    for (int g2 = 0; g2 < 2; ++g2) {
      const int dof = g2*32 + 8*fg;
      bf16x8 aH[2], aL[2];
      #pragma unroll
      for (int qt = 0; qt < 2; ++qt) {
        aH[qt] = *(const bf16x8*)&Ah[wq + qt*16 + fr][dof];
        aL[qt] = *(const bf16x8*)&Al[wq + qt*16 + fr][dof];
      }
      #pragma unroll
      for (int kt = 0; kt < 4; ++kt) {
        const bf16x8 bH = *(const bf16x8*)&Bh[wk + kt*16 + fr][dof];
        const bf16x8 bL = *(const bf16x8*)&Bl[wk + kt*16 + fr][dof];
        #pragma unroll
        for (int qt = 0; qt < 2; ++qt) {
          acc[qt][kt] = __builtin_amdgcn_mfma_f32_16x16x32_bf16(
              aH[qt], bH, acc[qt][kt], 0, 0, 0);
          acc[qt][kt] = __builtin_amdgcn_mfma_f32_16x16x32_bf16(
              aH[qt], bL, acc[qt][kt], 0, 0, 0);
          acc[qt][kt] = __builtin_amdgcn_mfma_f32_16x16x32_bf16(
              aL[qt], bH, acc[qt][kt], 0, 0, 0);
        }
      }
    }
  }

  float bcol[4];
  #pragma unroll
  for (int kt = 0; kt < 4; ++kt) bcol[kt] = bias[n0 + wk + kt*16 + fr];

  #pragma unroll
  for (int qt = 0; qt < 2; ++qt) {
    #pragma unroll
    for (int j = 0; j < 4; ++j) {
      const int m = m0 + wq + qt*16 + 4*fg + j;
      #pragma unroll
      for (int kt = 0; kt < 4; ++kt) {
        const int col = n0 + wk + kt*16 + fr;
        out[(size_t)m * Cch + col] = acc[qt][kt][j] + bcol[kt];
      }
    }
  }
}

} // anonymous namespace

// ---------------------------------------------------------------------------
extern "C" void kernel_launch(void* const* d_in, const int* in_sizes, int n_in,
                              void* d_out, int out_size, void* d_ws, size_t ws_size,
                              hipStream_t stream) {
  (void)in_sizes; (void)n_in; (void)out_size; (void)ws_size;

  const float* hid  = (const float*)d_in[0];
  const float* cnt  = (const float*)d_in[1];
  const float* Wq   = (const float*)d_in[2];
  const float* bq   = (const float*)d_in[3];
  const float* Wk   = (const float*)d_in[4];
  const float* bk   = (const float*)d_in[5];
  const float* Wv   = (const float*)d_in[6];
  const float* bv   = (const float*)d_in[7];
  const float* Wo   = (const float*)d_in[8];
  const float* bo   = (const float*)d_in[9];
  const int* counter = (const int*)d_in[10];
  const int* ucb     = (const int*)d_in[11];

  float* out       = (float*)d_out;          // [B,T,C]
  float* probs     = out + BTC;              // [B,H,T,T]
  float* count_out = probs + PROBSN;         // [B,H,T,T]

  // workspace: Qbf16(hi|lo) | Kbf16(hi|lo) | V f32 | ctx f32 (4 x BTC f32)
  float* ws  = (float*)d_ws;
  float* V   = ws + 2*BTC;
  float* ctx = ws + 3*BTC;
  unsigned short* qkb = (unsigned short*)d_ws;
  unsigned short* qh = qkb;
  unsigned short* ql = qkb + BTC;
  unsigned short* kh = qkb + 2*BTC;
  unsigned short* kl = qkb + 3*BTC;

  // pre-convert scratch lives in the count_out region of d_out (dead until
  // score_topk writes it; all consumers run before score_topk).
  unsigned short* cvt  = (unsigned short*)count_out;
  unsigned short* hidh = cvt;
  unsigned short* hidl = cvt + BTC;
  unsigned short* wqth = cvt + 2*BTC;
  unsigned short* wqtl = wqth + CC;
  unsigned short* wkth = wqtl + CC;
  unsigned short* wktl = wkth + CC;
  unsigned short* wvth = wktl + CC;
  unsigned short* wvtl = wvth + CC;

  // post-topk converts reuse the then-dead Q/K bf16 regions.
  unsigned short* ctxh = qkb;
  unsigned short* ctxl = qkb + BTC;
  unsigned short* woth = qkb + 2*BTC;
  unsigned short* wotl = woth + CC;

  split_plane<<<BTC/1024, 256, 0, stream>>>(hid, hidh, hidl);
  splitT_w<<<dim3(24, 24), 256, 0, stream>>>(Wq, wqth, wqtl);
  splitT_w<<<dim3(24, 24), 256, 0, stream>>>(Wk, wkth, wktl);
  splitT_w<<<dim3(24, 24), 256, 0, stream>>>(Wv, wvth, wvtl);

  qkv_mfma<<<dim3(Cch/128, (Bc*Tc)/64, 3), 256, 0, stream>>>(
      hidh, hidl, wqth, wqtl, wkth, wktl, wvth, wvtl,
      bq, bk, bv, qh, ql, kh, kl, V);

  score_topk<<<dim3(Tc/16, Bc*Hc), 1024, 0, stream>>>(
      qh, ql, kh, kl, ws, cnt, counter, ucb, probs, count_out, ctx);

  pv_gemm<<<dim3(Tc/64, Bc*Hc), 256, 0, stream>>>(
      probs, V, ctx, counter, ucb);

  split_plane<<<BTC/1024, 256, 0, stream>>>(ctx, ctxh, ctxl);
  splitT_w<<<dim3(24, 24), 256, 0, stream>>>(Wo, woth, wotl);

  out_mfma<<<dim3(Cch/128, (Bc*Tc)/64), 256, 0, stream>>>(
      ctxh, ctxl, woth, wotl, bo, out);
}

// Round 11
// 414.484 us; speedup vs baseline: 1.1951x; 1.1951x over previous
//
#include <hip/hip_runtime.h>
#include <math.h>

namespace {

constexpr int Bc = 4, Tc = 1024, Cch = 768, Hc = 12, Dc = 64, KSEL = 10;
constexpr size_t BTC    = (size_t)Bc * Tc * Cch;        // 3,145,728
constexpr size_t PROBSN = (size_t)Bc * Hc * Tc * Tc;    // 50,331,648
constexpr size_t CC     = (size_t)Cch * Cch;            // 589,824

typedef __attribute__((ext_vector_type(8))) short          bf16x8;
typedef __attribute__((ext_vector_type(4))) float          f32x4;
typedef __attribute__((ext_vector_type(4))) unsigned short u16x4;
typedef __attribute__((ext_vector_type(8))) unsigned short u16x8;

// round-to-nearest-even f32 -> bf16 (raw bits); finite inputs only
__device__ __forceinline__ unsigned short bf16rne(float x) {
  unsigned int u = __float_as_uint(x);
  return (unsigned short)((u + 0x7FFFu + ((u >> 16) & 1u)) >> 16);
}
__device__ __forceinline__ float bf16tof(unsigned short h) {
  return __uint_as_float(((unsigned int)h) << 16);
}

// ---------------------------------------------------------------------------
// split_plane: f32[n] -> bf16 hi/lo planes.  n multiple of 1024.
// ---------------------------------------------------------------------------
__global__ __launch_bounds__(256) void split_plane(
    const float* __restrict__ src,
    unsigned short* __restrict__ h, unsigned short* __restrict__ l)
{
  const size_t i = (size_t)(blockIdx.x * 256 + threadIdx.x) * 4;
  const float4 v = *(const float4*)&src[i];
  const float xs[4] = {v.x, v.y, v.z, v.w};
  u16x4 hh, ll;
  #pragma unroll
  for (int e = 0; e < 4; ++e) {
    const unsigned short hb = bf16rne(xs[e]);
    hh[e] = hb;
    ll[e] = bf16rne(xs[e] - bf16tof(hb));
  }
  *(u16x4*)&h[i] = hh;
  *(u16x4*)&l[i] = ll;
}

// ---------------------------------------------------------------------------
// splitT_w: W[k][n] (768x768 f32) -> transposed bf16 planes th/tl [n][k].
// ---------------------------------------------------------------------------
__global__ __launch_bounds__(256) void splitT_w(
    const float* __restrict__ W,
    unsigned short* __restrict__ th, unsigned short* __restrict__ tl)
{
  __shared__ float tile[32][33];
  const int n0 = blockIdx.x * 32, k0 = blockIdx.y * 32;
  const int x = threadIdx.x & 31, y = threadIdx.x >> 5;   // y 0..7

  #pragma unroll
  for (int i = 0; i < 4; ++i) {
    const int kk = y * 4 + i;
    tile[kk][x] = W[(size_t)(k0 + kk) * Cch + n0 + x];
  }
  __syncthreads();
  #pragma unroll
  for (int i = 0; i < 4; ++i) {
    const int nn = y * 4 + i;
    const float v = tile[x][nn];                          // = W[k0+x][n0+nn]
    const unsigned short hb = bf16rne(v);
    th[(size_t)(n0 + nn) * Cch + k0 + x] = hb;
    tl[(size_t)(n0 + nn) * Cch + k0 + x] = bf16rne(v - bf16tof(hb));
  }
}

// ---------------------------------------------------------------------------
// qkv_mfma: [Q|K|V] = hid @ W + b, split-bf16 MFMA.  (unchanged)
// ---------------------------------------------------------------------------
__global__ __launch_bounds__(256) void qkv_mfma(
    const unsigned short* __restrict__ hidh, const unsigned short* __restrict__ hidl,
    const unsigned short* __restrict__ wqth, const unsigned short* __restrict__ wqtl,
    const unsigned short* __restrict__ wkth, const unsigned short* __restrict__ wktl,
    const unsigned short* __restrict__ wvth, const unsigned short* __restrict__ wvtl,
    const float* __restrict__ bq, const float* __restrict__ bk,
    const float* __restrict__ bv,
    unsigned short* __restrict__ qh, unsigned short* __restrict__ ql,
    unsigned short* __restrict__ kh, unsigned short* __restrict__ kl,
    float* __restrict__ V)
{
  const int z = blockIdx.z;
  const unsigned short* __restrict__ Bhp = (z == 0) ? wqth : (z == 1) ? wkth : wvth;
  const unsigned short* __restrict__ Blp = (z == 0) ? wqtl : (z == 1) ? wktl : wvtl;
  const float* __restrict__ bias = (z == 0) ? bq : (z == 1) ? bk : bv;

  const int m0 = blockIdx.y * 64;
  const int n0 = blockIdx.x * 128;

  __shared__ unsigned short Ah[64][72],  Al[64][72];
  __shared__ unsigned short Bh[128][72], Bl[128][72];

  const int t    = threadIdx.x;
  const int lane = t & 63;
  const int wv   = t >> 6;
  const int wq   = (wv >> 1) * 32;
  const int wk   = (wv & 1) * 64;
  const int fr   = lane & 15;
  const int fg   = lane >> 4;

  f32x4 acc[2][4] = {};

  for (int k0 = 0; k0 < Cch; k0 += 64) {
    __syncthreads();
    #pragma unroll
    for (int i = 0; i < 2; ++i) {       // A: 64x64 x 2 planes
      const int id = t + 256*i;
      const int r = id >> 3, c8 = (id & 7) * 8;
      *(u16x8*)&Ah[r][c8] = *(const u16x8*)&hidh[(size_t)(m0 + r)*Cch + k0 + c8];
      *(u16x8*)&Al[r][c8] = *(const u16x8*)&hidl[(size_t)(m0 + r)*Cch + k0 + c8];
    }
    #pragma unroll
    for (int i = 0; i < 4; ++i) {       // B: 128x64 x 2 planes
      const int id = t + 256*i;
      const int r = id >> 3, c8 = (id & 7) * 8;
      *(u16x8*)&Bh[r][c8] = *(const u16x8*)&Bhp[(size_t)(n0 + r)*Cch + k0 + c8];
      *(u16x8*)&Bl[r][c8] = *(const u16x8*)&Blp[(size_t)(n0 + r)*Cch + k0 + c8];
    }
    __syncthreads();

    #pragma unroll
    for (int g2 = 0; g2 < 2; ++g2) {
      const int dof = g2*32 + 8*fg;
      bf16x8 aH[2], aL[2];
      #pragma unroll
      for (int qt = 0; qt < 2; ++qt) {
        aH[qt] = *(const bf16x8*)&Ah[wq + qt*16 + fr][dof];
        aL[qt] = *(const bf16x8*)&Al[wq + qt*16 + fr][dof];
      }
      #pragma unroll
      for (int kt = 0; kt < 4; ++kt) {
        const bf16x8 bH = *(const bf16x8*)&Bh[wk + kt*16 + fr][dof];
        const bf16x8 bL = *(const bf16x8*)&Bl[wk + kt*16 + fr][dof];
        #pragma unroll
        for (int qt = 0; qt < 2; ++qt) {
          acc[qt][kt] = __builtin_amdgcn_mfma_f32_16x16x32_bf16(
              aH[qt], bH, acc[qt][kt], 0, 0, 0);
          acc[qt][kt] = __builtin_amdgcn_mfma_f32_16x16x32_bf16(
              aH[qt], bL, acc[qt][kt], 0, 0, 0);
          acc[qt][kt] = __builtin_amdgcn_mfma_f32_16x16x32_bf16(
              aL[qt], bH, acc[qt][kt], 0, 0, 0);
        }
      }
    }
  }

  float bcol[4];
  #pragma unroll
  for (int kt = 0; kt < 4; ++kt) bcol[kt] = bias[n0 + wk + kt*16 + fr];

  unsigned short* __restrict__ dh = (z == 0) ? qh : kh;
  unsigned short* __restrict__ dl = (z == 0) ? ql : kl;

  #pragma unroll
  for (int qt = 0; qt < 2; ++qt) {
    #pragma unroll
    for (int j = 0; j < 4; ++j) {
      const int m  = m0 + wq + qt*16 + 4*fg + j;
      const int b  = m >> 10, tt = m & 1023;
      #pragma unroll
      for (int kt = 0; kt < 4; ++kt) {
        const int col = n0 + wk + kt*16 + fr;
        const float val = acc[qt][kt][j] + bcol[kt];
        const size_t idx =
            (((size_t)(b*Hc + (col >> 6)))*Tc + tt)*Dc + (col & 63);
        if (z < 2) {
          const unsigned short hb = bf16rne(val);
          dh[idx] = hb;
          dl[idx] = bf16rne(val - bf16tof(hb));
        } else {
          V[idx] = val;
        }
      }
    }
  }
}

// ---------------------------------------------------------------------------
// score_mfma: scores = 0.125 * Q @ K^T, split-bf16 MFMA.  (round-9 proven)
// ---------------------------------------------------------------------------
__global__ __launch_bounds__(256) void score_mfma(
    const unsigned short* __restrict__ qhp, const unsigned short* __restrict__ qlp,
    const unsigned short* __restrict__ khp, const unsigned short* __restrict__ klp,
    float* __restrict__ scores)
{
  const int k0 = blockIdx.x * 128;
  const int q0 = blockIdx.y * 64;
  const int bh = blockIdx.z;

  __shared__ unsigned short Qh[64][72],  Ql[64][72];
  __shared__ unsigned short Kh[128][72], Kl[128][72];

  const int t = threadIdx.x;
  const size_t qb = ((size_t)bh*Tc + q0) * Dc;
  const size_t kb = ((size_t)bh*Tc + k0) * Dc;

  #pragma unroll
  for (int i = 0; i < 2; ++i) {
    const int id = t + 256*i;
    const int r = id >> 3, c8 = (id & 7) * 8;
    *(u16x8*)&Qh[r][c8] = *(const u16x8*)&qhp[qb + (size_t)r*Dc + c8];
    *(u16x8*)&Ql[r][c8] = *(const u16x8*)&qlp[qb + (size_t)r*Dc + c8];
  }
  #pragma unroll
  for (int i = 0; i < 4; ++i) {
    const int id = t + 256*i;
    const int r = id >> 3, c8 = (id & 7) * 8;
    *(u16x8*)&Kh[r][c8] = *(const u16x8*)&khp[kb + (size_t)r*Dc + c8];
    *(u16x8*)&Kl[r][c8] = *(const u16x8*)&klp[kb + (size_t)r*Dc + c8];
  }
  __syncthreads();

  const int lane = t & 63;
  const int wv   = t >> 6;
  const int wq   = (wv >> 1) * 32;
  const int wk   = (wv & 1) * 64;
  const int fr   = lane & 15;
  const int fg   = lane >> 4;

  f32x4 acc[2][4] = {};

  #pragma unroll
  for (int g2 = 0; g2 < 2; ++g2) {
    const int dof = g2*32 + 8*fg;
    bf16x8 aH[2], aL[2];
    #pragma unroll
    for (int qt = 0; qt < 2; ++qt) {
      aH[qt] = *(const bf16x8*)&Qh[wq + qt*16 + fr][dof];
      aL[qt] = *(const bf16x8*)&Ql[wq + qt*16 + fr][dof];
    }
    #pragma unroll
    for (int kt = 0; kt < 4; ++kt) {
      const bf16x8 bH = *(const bf16x8*)&Kh[wk + kt*16 + fr][dof];
      const bf16x8 bL = *(const bf16x8*)&Kl[wk + kt*16 + fr][dof];
      #pragma unroll
      for (int qt = 0; qt < 2; ++qt) {
        acc[qt][kt] = __builtin_amdgcn_mfma_f32_16x16x32_bf16(
            aH[qt], bH, acc[qt][kt], 0, 0, 0);
        acc[qt][kt] = __builtin_amdgcn_mfma_f32_16x16x32_bf16(
            aH[qt], bL, acc[qt][kt], 0, 0, 0);
        acc[qt][kt] = __builtin_amdgcn_mfma_f32_16x16x32_bf16(
            aL[qt], bH, acc[qt][kt], 0, 0, 0);
      }
    }
  }

  #pragma unroll
  for (int qt = 0; qt < 2; ++qt) {
    #pragma unroll
    for (int j = 0; j < 4; ++j) {
      const int qrow = q0 + wq + qt*16 + 4*fg + j;
      const size_t rb = ((size_t)bh * Tc + qrow) * Tc + k0 + wk;
      #pragma unroll
      for (int kt = 0; kt < 4; ++kt)
        scores[rb + kt*16 + fr] = acc[qt][kt][j] * 0.125f;
    }
  }
}

// ---------------------------------------------------------------------------
// ucb_topk: softmax + UCB top-k + renorm + count + sparse PV.
// TWO rows per wave (A/B), round chains interleaved to hide shfl latency.
// Scan: f32 linear argmax carrying w (strict '>' keeps lowest w = lowest
// index within lane).  Butterfly: (u, k) with k = lane + 64w; tie -> lower k.
// Exactly jax.lax.top_k's (value, lowest-index) semantics.
// ---------------------------------------------------------------------------
__global__ __launch_bounds__(256, 2) void ucb_topk(
    const float* __restrict__ qkv,
    const float* __restrict__ count_in,
    const int*   __restrict__ counter_p,
    const int*   __restrict__ ucb_p,
    float* __restrict__ probs,          // in: scaled scores; out: probs
    float* __restrict__ count_out,
    float* __restrict__ ctx)
{
  const int bh   = blockIdx.y;
  const int lane = threadIdx.x & 63;
  const int wv   = threadIdx.x >> 6;        // 0..3
  const int rowA = blockIdx.x * 8 + wv * 2;
  const int rowB = rowA + 1;
  const int b = bh / Hc, h = bh % Hc;
  const size_t rbA = ((size_t)bh * Tc + rowA) * Tc;
  const size_t rbB = ((size_t)bh * Tc + rowB) * Tc;
  const float* __restrict__ Vh = qkv + 2*BTC + (size_t)bh * Tc * Dc;

  __shared__ float psel[8][KSEL];     // winner s values, per row-in-block

  const int  counter = counter_p[0];
  const int  ucbf    = ucb_p[0];
  const bool do_ucb  = (ucbf != 0) && (counter >= 1000);
  const float lt     = do_ucb ? logf((float)counter) : 0.f;

  float sA[16], sB[16];
  #pragma unroll
  for (int w = 0; w < 16; ++w) sA[w] = probs[rbA + lane + 64*w];
  #pragma unroll
  for (int w = 0; w < 16; ++w) sB[w] = probs[rbB + lane + 64*w];

  // softmax, both rows interleaved
  float mxA = -INFINITY, mxB = -INFINITY;
  #pragma unroll
  for (int w = 0; w < 16; ++w) { mxA = fmaxf(mxA, sA[w]); mxB = fmaxf(mxB, sB[w]); }
  #pragma unroll
  for (int off = 32; off > 0; off >>= 1) {
    mxA = fmaxf(mxA, __shfl_xor(mxA, off));
    mxB = fmaxf(mxB, __shfl_xor(mxB, off));
  }
  float smA = 0.f, smB = 0.f;
  #pragma unroll
  for (int w = 0; w < 16; ++w) {
    sA[w] = __expf(sA[w] - mxA); smA += sA[w];
    sB[w] = __expf(sB[w] - mxB); smB += sB[w];
  }
  #pragma unroll
  for (int off = 32; off > 0; off >>= 1) {
    smA += __shfl_xor(smA, off);
    smB += __shfl_xor(smB, off);
  }
  const float rsA = 1.0f / smA, rsB = 1.0f / smB;
  #pragma unroll
  for (int w = 0; w < 16; ++w) { sA[w] *= rsA; sB[w] *= rsB; }   // att

  if (do_ucb) {
    const float sqlt = sqrtf(lt);

    float uA[16], uB[16];
    #pragma unroll
    for (int w = 0; w < 16; ++w) {
      const float cA = count_in[rbA + lane + 64*w];
      count_out[rbA + lane + 64*w] = cA;
      uA[w] = fmaf(sqlt, rsqrtf(cA + 1e-8f), sA[w]);
      const float cB = count_in[rbB + lane + 64*w];
      count_out[rbB + lane + 64*w] = cB;
      uB[w] = fmaf(sqlt, rsqrtf(cB + 1e-8f), sB[w]);
    }

    unsigned selA = 0u, selB = 0u;
    unsigned long long rpA = 0ull, rpB = 0ull;   // 4-bit round id per w slot
    int ksA[KSEL], ksB[KSEL];                    // wave-uniform (SGPR)

    #pragma unroll
    for (int r = 0; r < KSEL; ++r) {
      // lane-local argmax over unselected, strict '>' keeps lowest w
      float bvA = ((selA >> 0) & 1u) ? -INFINITY : uA[0];  int bwA = 0;
      float bvB = ((selB >> 0) & 1u) ? -INFINITY : uB[0];  int bwB = 0;
      #pragma unroll
      for (int w = 1; w < 16; ++w) {
        const float tA = ((selA >> w) & 1u) ? -INFINITY : uA[w];
        if (tA > bvA) { bvA = tA; bwA = w; }
        const float tB = ((selB >> w) & 1u) ? -INFINITY : uB[w];
        if (tB > bvB) { bvB = tB; bwB = w; }
      }
      int kA = lane + (bwA << 6);
      int kB = lane + (bwB << 6);
      // butterfly max on (u, k), tie -> lower k; A/B interleaved
      #pragma unroll
      for (int off = 32; off > 0; off >>= 1) {
        const float ovA = __shfl_xor(bvA, off);
        const int   okA = __shfl_xor(kA,  off);
        const float ovB = __shfl_xor(bvB, off);
        const int   okB = __shfl_xor(kB,  off);
        if (ovA > bvA || (ovA == bvA && okA < kA)) { bvA = ovA; kA = okA; }
        if (ovB > bvB || (ovB == bvB && okB < kB)) { bvB = ovB; kB = okB; }
      }
      ksA[r] = __builtin_amdgcn_readfirstlane(kA);
      ksB[r] = __builtin_amdgcn_readfirstlane(kB);
      if ((kA & 63) == lane) {
        const int wsel = kA >> 6;
        selA |= 1u << wsel;
        rpA  |= ((unsigned long long)r) << (4 * wsel);
      }
      if ((kB & 63) == lane) {
        const int wsel = kB >> 6;
        selB |= 1u << wsel;
        rpB  |= ((unsigned long long)r) << (4 * wsel);
      }
    }

    // publish winner s values (owner lanes) to LDS, keyed by round id
    #pragma unroll
    for (int w = 0; w < 16; ++w) {
      if ((selA >> w) & 1u)
        psel[2*wv    ][(int)((rpA >> (4 * w)) & 15ull)] = sA[w];
      if ((selB >> w) & 1u)
        psel[2*wv + 1][(int)((rpB >> (4 * w)) & 15ull)] = sB[w];
    }
    __syncthreads();    // do_ucb is grid-uniform; all waves reach this

    float pvvA[KSEL], pvvB[KSEL];
    float denA = 1e-8f, denB = 1e-8f;
    #pragma unroll
    for (int r = 0; r < KSEL; ++r) {
      pvvA[r] = psel[2*wv][r];     denA += pvvA[r];
      pvvB[r] = psel[2*wv + 1][r]; denB += pvvB[r];
    }
    const float rdA = 1.0f / denA, rdB = 1.0f / denB;

    #pragma unroll
    for (int w = 0; w < 16; ++w) {
      probs[rbA + lane + 64*w] = ((selA >> w) & 1u) ? (sA[w] * rdA) : 0.0f;
      probs[rbB + lane + 64*w] = ((selB >> w) & 1u) ? (sB[w] * rdB) : 0.0f;
    }
    #pragma unroll
    for (int r = 0; r < KSEL; ++r) {
      if ((ksA[r] & 63) == lane)
        count_out[rbA + ksA[r]] = count_in[rbA + ksA[r]] + 1.0f;
      if ((ksB[r] & 63) == lane)
        count_out[rbB + ksB[r]] = count_in[rbB + ksB[r]] + 1.0f;
    }

    float cdA = 0.f, cdB = 0.f;
    #pragma unroll
    for (int r = 0; r < KSEL; ++r) {
      cdA += pvvA[r] * Vh[(size_t)ksA[r] * Dc + lane];
      cdB += pvvB[r] * Vh[(size_t)ksB[r] * Dc + lane];
    }
    ctx[((size_t)b*Tc + rowA)*Cch + h*Dc + lane] = cdA * rdA;
    ctx[((size_t)b*Tc + rowB)*Cch + h*Dc + lane] = cdB * rdB;
  } else {
    #pragma unroll
    for (int w = 0; w < 16; ++w) {
      probs[rbA + lane + 64*w]     = sA[w];
      count_out[rbA + lane + 64*w] = count_in[rbA + lane + 64*w];
      probs[rbB + lane + 64*w]     = sB[w];
      count_out[rbB + lane + 64*w] = count_in[rbB + lane + 64*w];
    }
  }
}

// ---------------------------------------------------------------------------
// K3 (fallback only, non-UCB path): ctx = probs @ V per (b,h).
// ---------------------------------------------------------------------------
__global__ __launch_bounds__(256) void pv_gemm(
    const float* __restrict__ probs,
    const float* __restrict__ Vm,
    float* __restrict__ ctx,
    const int* __restrict__ counter_p,
    const int* __restrict__ ucb_p)
{
  if ((ucb_p[0] != 0) && (counter_p[0] >= 1000)) return;  // topk did sparse PV

  const int bh = blockIdx.y;
  const int q0 = blockIdx.x * 64;
  const int b = bh / Hc, h = bh % Hc;

  __shared__ float aT[32][68];
  __shared__ float vN[32][68];

  const int t  = threadIdx.x;
  const int tn = t & 15;
  const int tq = t >> 4;

  float acc[4][4];
  #pragma unroll
  for (int i = 0; i < 4; ++i)
    #pragma unroll
    for (int j = 0; j < 4; ++j) acc[i][j] = 0.f;

  for (int k0 = 0; k0 < Tc; k0 += 32) {
    __syncthreads();
    #pragma unroll
    for (int p = 0; p < 2; ++p) {
      const int id = t + 256*p;
      const int r = id >> 3, c = id & 7;
      const float4 v =
          *(const float4*)&probs[((size_t)bh*Tc + q0 + r)*Tc + k0 + 4*c];
      aT[4*c + 0][r] = v.x; aT[4*c + 1][r] = v.y;
      aT[4*c + 2][r] = v.z; aT[4*c + 3][r] = v.w;
    }
    #pragma unroll
    for (int p = 0; p < 2; ++p) {
      const int id = t + 256*p;
      const int kk = id >> 4, dcc = id & 15;
      const float4 v = *(const float4*)&Vm[((size_t)bh*Tc + k0 + kk)*Dc + 4*dcc];
      *(float4*)&vN[kk][4*dcc] = v;
    }
    __syncthreads();
    #pragma unroll
    for (int kk = 0; kk < 32; ++kk) {
      const float4 a  = *(const float4*)&aT[kk][4*tq];
      const float4 vv = *(const float4*)&vN[kk][4*tn];
      const float av[4] = {a.x, a.y, a.z, a.w};
      const float bw[4] = {vv.x, vv.y, vv.z, vv.w};
      #pragma unroll
      for (int qi = 0; qi < 4; ++qi)
        #pragma unroll
        for (int ni = 0; ni < 4; ++ni) acc[qi][ni] += av[qi] * bw[ni];
    }
  }

  #pragma unroll
  for (int qi = 0; qi < 4; ++qi) {
    const int tt = q0 + 4*tq + qi;
    float4 o;
    o.x = acc[qi][0]; o.y = acc[qi][1]; o.z = acc[qi][2]; o.w = acc[qi][3];
    *(float4*)&ctx[((size_t)b*Tc + tt)*Cch + h*Dc + 4*tn] = o;
  }
}

// ---------------------------------------------------------------------------
// out_mfma: out = ctx @ Wo + bo, split-bf16 MFMA.  (unchanged)
// ---------------------------------------------------------------------------
__global__ __launch_bounds__(256) void out_mfma(
    const unsigned short* __restrict__ ah, const unsigned short* __restrict__ al,
    const unsigned short* __restrict__ bth, const unsigned short* __restrict__ btl,
    const float* __restrict__ bias,
    float* __restrict__ out)
{
  const int m0 = blockIdx.y * 64;
  const int n0 = blockIdx.x * 128;

  __shared__ unsigned short Ah[64][72],  Al[64][72];
  __shared__ unsigned short Bh[128][72], Bl[128][72];

  const int t    = threadIdx.x;
  const int lane = t & 63;
  const int wv   = t >> 6;
  const int wq   = (wv >> 1) * 32;
  const int wk   = (wv & 1) * 64;
  const int fr   = lane & 15;
  const int fg   = lane >> 4;

  f32x4 acc[2][4] = {};

  for (int k0 = 0; k0 < Cch; k0 += 64) {
    __syncthreads();
    #pragma unroll
    for (int i = 0; i < 2; ++i) {
      const int id = t + 256*i;
      const int r = id >> 3, c8 = (id & 7) * 8;
      *(u16x8*)&Ah[r][c8] = *(const u16x8*)&ah[(size_t)(m0 + r)*Cch + k0 + c8];
      *(u16x8*)&Al[r][c8] = *(const u16x8*)&al[(size_t)(m0 + r)*Cch + k0 + c8];
    }
    #pragma unroll
    for (int i = 0; i < 4; ++i) {
      const int id = t + 256*i;
      const int r = id >> 3, c8 = (id & 7) * 8;
      *(u16x8*)&Bh[r][c8] = *(const u16x8*)&bth[(size_t)(n0 + r)*Cch + k0 + c8];
      *(u16x8*)&Bl[r][c8] = *(const u16x8*)&btl[(size_t)(n0 + r)*Cch + k0 + c8];
    }
    __syncthreads();

    #pragma unroll
    for (int g2 = 0; g2 < 2; ++g2) {
      const int dof = g2*32 + 8*fg;
      bf16x8 aH[2], aL[2];
      #pragma unroll
      for (int qt = 0; qt < 2; ++qt) {
        aH[qt] = *(const bf16x8*)&Ah[wq + qt*16 + fr][dof];
        aL[qt] = *(const bf16x8*)&Al[wq + qt*16 + fr][dof];
      }
      #pragma unroll
      for (int kt = 0; kt < 4; ++kt) {
        const bf16x8 bH = *(const bf16x8*)&Bh[wk + kt*16 + fr][dof];
        const bf16x8 bL = *(const bf16x8*)&Bl[wk + kt*16 + fr][dof];
        #pragma unroll
        for (int qt = 0; qt < 2; ++qt) {
          acc[qt][kt] = __builtin_amdgcn_mfma_f32_16x16x32_bf16(
              aH[qt], bH, acc[qt][kt], 0, 0, 0);
          acc[qt][kt] = __builtin_amdgcn_mfma_f32_16x16x32_bf16(
              aH[qt], bL, acc[qt][kt], 0, 0, 0);
          acc[qt][kt] = __builtin_amdgcn_mfma_f32_16x16x32_bf16(
              aL[qt], bH, acc[qt][kt], 0, 0, 0);
        }
      }
    }
  }

  float bcol[4];
  #pragma unroll
  for (int kt = 0; kt < 4; ++kt) bcol[kt] = bias[n0 + wk + kt*16 + fr];

  #pragma unroll
  for (int qt = 0; qt < 2; ++qt) {
    #pragma unroll
    for (int j = 0; j < 4; ++j) {
      const int m = m0 + wq + qt*16 + 4*fg + j;
      #pragma unroll
      for (int kt = 0; kt < 4; ++kt) {
        const int col = n0 + wk + kt*16 + fr;
        out[(size_t)m * Cch + col] = acc[qt][kt][j] + bcol[kt];
      }
    }
  }
}

} // anonymous namespace

// ---------------------------------------------------------------------------
extern "C" void kernel_launch(void* const* d_in, const int* in_sizes, int n_in,
                              void* d_out, int out_size, void* d_ws, size_t ws_size,
                              hipStream_t stream) {
  (void)in_sizes; (void)n_in; (void)out_size; (void)ws_size;

  const float* hid  = (const float*)d_in[0];
  const float* cnt  = (const float*)d_in[1];
  const float* Wq   = (const float*)d_in[2];
  const float* bq   = (const float*)d_in[3];
  const float* Wk   = (const float*)d_in[4];
  const float* bk   = (const float*)d_in[5];
  const float* Wv   = (const float*)d_in[6];
  const float* bv   = (const float*)d_in[7];
  const float* Wo   = (const float*)d_in[8];
  const float* bo   = (const float*)d_in[9];
  const int* counter = (const int*)d_in[10];
  const int* ucb     = (const int*)d_in[11];

  float* out       = (float*)d_out;          // [B,T,C]
  float* probs     = out + BTC;              // [B,H,T,T] (scores, then probs)
  float* count_out = probs + PROBSN;         // [B,H,T,T]

  // workspace: Qbf16(hi|lo) | Kbf16(hi|lo) | V f32 | ctx f32 (4 x BTC f32)
  float* ws  = (float*)d_ws;
  float* V   = ws + 2*BTC;
  float* ctx = ws + 3*BTC;
  unsigned short* qkb = (unsigned short*)d_ws;
  unsigned short* qh = qkb;
  unsigned short* ql = qkb + BTC;
  unsigned short* kh = qkb + 2*BTC;
  unsigned short* kl = qkb + 3*BTC;

  // pre-convert scratch lives in the count_out region of d_out (dead until
  // ucb_topk writes it; all consumers run before ucb_topk).
  unsigned short* cvt  = (unsigned short*)count_out;
  unsigned short* hidh = cvt;
  unsigned short* hidl = cvt + BTC;
  unsigned short* wqth = cvt + 2*BTC;
  unsigned short* wqtl = wqth + CC;
  unsigned short* wkth = wqtl + CC;
  unsigned short* wktl = wkth + CC;
  unsigned short* wvth = wktl + CC;
  unsigned short* wvtl = wvth + CC;

  // post-topk converts reuse the then-dead Q/K bf16 regions.
  unsigned short* ctxh = qkb;
  unsigned short* ctxl = qkb + BTC;
  unsigned short* woth = qkb + 2*BTC;
  unsigned short* wotl = woth + CC;

  split_plane<<<BTC/1024, 256, 0, stream>>>(hid, hidh, hidl);
  splitT_w<<<dim3(24, 24), 256, 0, stream>>>(Wq, wqth, wqtl);
  splitT_w<<<dim3(24, 24), 256, 0, stream>>>(Wk, wkth, wktl);
  splitT_w<<<dim3(24, 24), 256, 0, stream>>>(Wv, wvth, wvtl);

  qkv_mfma<<<dim3(Cch/128, (Bc*Tc)/64, 3), 256, 0, stream>>>(
      hidh, hidl, wqth, wqtl, wkth, wktl, wvth, wvtl,
      bq, bk, bv, qh, ql, kh, kl, V);

  score_mfma<<<dim3(Tc/128, Tc/64, Bc*Hc), 256, 0, stream>>>(
      qh, ql, kh, kl, probs);

  ucb_topk<<<dim3(Tc/8, Bc*Hc), 256, 0, stream>>>(
      ws, cnt, counter, ucb, probs, count_out, ctx);

  pv_gemm<<<dim3(Tc/64, Bc*Hc), 256, 0, stream>>>(
      probs, V, ctx, counter, ucb);

  split_plane<<<BTC/1024, 256, 0, stream>>>(ctx, ctxh, ctxl);
  splitT_w<<<dim3(24, 24), 256, 0, stream>>>(Wo, woth, wotl);

  out_mfma<<<dim3(Cch/128, (Bc*Tc)/64), 256, 0, stream>>>(
      ctxh, ctxl, woth, wotl, bo, out);
}

// Round 12
// 410.986 us; speedup vs baseline: 1.2053x; 1.0085x over previous
//
#include <hip/hip_runtime.h>
#include <math.h>

namespace {

constexpr int Bc = 4, Tc = 1024, Cch = 768, Hc = 12, Dc = 64, KSEL = 10;
constexpr size_t BTC    = (size_t)Bc * Tc * Cch;        // 3,145,728
constexpr size_t PROBSN = (size_t)Bc * Hc * Tc * Tc;    // 50,331,648
constexpr size_t CC     = (size_t)Cch * Cch;            // 589,824

typedef __attribute__((ext_vector_type(8))) short          bf16x8;
typedef __attribute__((ext_vector_type(4))) float          f32x4;
typedef __attribute__((ext_vector_type(4))) unsigned short u16x4;
typedef __attribute__((ext_vector_type(8))) unsigned short u16x8;

// round-to-nearest-even f32 -> bf16 (raw bits); finite inputs only
__device__ __forceinline__ unsigned short bf16rne(float x) {
  unsigned int u = __float_as_uint(x);
  return (unsigned short)((u + 0x7FFFu + ((u >> 16) & 1u)) >> 16);
}
__device__ __forceinline__ float bf16tof(unsigned short h) {
  return __uint_as_float(((unsigned int)h) << 16);
}

// ---------------------------------------------------------------------------
// split_plane: f32[n] -> bf16 hi/lo planes.  n multiple of 1024.
// ---------------------------------------------------------------------------
__global__ __launch_bounds__(256) void split_plane(
    const float* __restrict__ src,
    unsigned short* __restrict__ h, unsigned short* __restrict__ l)
{
  const size_t i = (size_t)(blockIdx.x * 256 + threadIdx.x) * 4;
  const float4 v = *(const float4*)&src[i];
  const float xs[4] = {v.x, v.y, v.z, v.w};
  u16x4 hh, ll;
  #pragma unroll
  for (int e = 0; e < 4; ++e) {
    const unsigned short hb = bf16rne(xs[e]);
    hh[e] = hb;
    ll[e] = bf16rne(xs[e] - bf16tof(hb));
  }
  *(u16x4*)&h[i] = hh;
  *(u16x4*)&l[i] = ll;
}

// ---------------------------------------------------------------------------
// splitT_w: W[k][n] (768x768 f32) -> transposed bf16 planes th/tl [n][k].
// ---------------------------------------------------------------------------
__global__ __launch_bounds__(256) void splitT_w(
    const float* __restrict__ W,
    unsigned short* __restrict__ th, unsigned short* __restrict__ tl)
{
  __shared__ float tile[32][33];
  const int n0 = blockIdx.x * 32, k0 = blockIdx.y * 32;
  const int x = threadIdx.x & 31, y = threadIdx.x >> 5;   // y 0..7

  #pragma unroll
  for (int i = 0; i < 4; ++i) {
    const int kk = y * 4 + i;
    tile[kk][x] = W[(size_t)(k0 + kk) * Cch + n0 + x];
  }
  __syncthreads();
  #pragma unroll
  for (int i = 0; i < 4; ++i) {
    const int nn = y * 4 + i;
    const float v = tile[x][nn];                          // = W[k0+x][n0+nn]
    const unsigned short hb = bf16rne(v);
    th[(size_t)(n0 + nn) * Cch + k0 + x] = hb;
    tl[(size_t)(n0 + nn) * Cch + k0 + x] = bf16rne(v - bf16tof(hb));
  }
}

// ---------------------------------------------------------------------------
// qkv_mfma: [Q|K|V] = hid @ W + b, split-bf16 MFMA.  (unchanged)
// ---------------------------------------------------------------------------
__global__ __launch_bounds__(256) void qkv_mfma(
    const unsigned short* __restrict__ hidh, const unsigned short* __restrict__ hidl,
    const unsigned short* __restrict__ wqth, const unsigned short* __restrict__ wqtl,
    const unsigned short* __restrict__ wkth, const unsigned short* __restrict__ wktl,
    const unsigned short* __restrict__ wvth, const unsigned short* __restrict__ wvtl,
    const float* __restrict__ bq, const float* __restrict__ bk,
    const float* __restrict__ bv,
    unsigned short* __restrict__ qh, unsigned short* __restrict__ ql,
    unsigned short* __restrict__ kh, unsigned short* __restrict__ kl,
    float* __restrict__ V)
{
  const int z = blockIdx.z;
  const unsigned short* __restrict__ Bhp = (z == 0) ? wqth : (z == 1) ? wkth : wvth;
  const unsigned short* __restrict__ Blp = (z == 0) ? wqtl : (z == 1) ? wktl : wvtl;
  const float* __restrict__ bias = (z == 0) ? bq : (z == 1) ? bk : bv;

  const int m0 = blockIdx.y * 64;
  const int n0 = blockIdx.x * 128;

  __shared__ unsigned short Ah[64][72],  Al[64][72];
  __shared__ unsigned short Bh[128][72], Bl[128][72];

  const int t    = threadIdx.x;
  const int lane = t & 63;
  const int wv   = t >> 6;
  const int wq   = (wv >> 1) * 32;
  const int wk   = (wv & 1) * 64;
  const int fr   = lane & 15;
  const int fg   = lane >> 4;

  f32x4 acc[2][4] = {};

  for (int k0 = 0; k0 < Cch; k0 += 64) {
    __syncthreads();
    #pragma unroll
    for (int i = 0; i < 2; ++i) {       // A: 64x64 x 2 planes
      const int id = t + 256*i;
      const int r = id >> 3, c8 = (id & 7) * 8;
      *(u16x8*)&Ah[r][c8] = *(const u16x8*)&hidh[(size_t)(m0 + r)*Cch + k0 + c8];
      *(u16x8*)&Al[r][c8] = *(const u16x8*)&hidl[(size_t)(m0 + r)*Cch + k0 + c8];
    }
    #pragma unroll
    for (int i = 0; i < 4; ++i) {       // B: 128x64 x 2 planes
      const int id = t + 256*i;
      const int r = id >> 3, c8 = (id & 7) * 8;
      *(u16x8*)&Bh[r][c8] = *(const u16x8*)&Bhp[(size_t)(n0 + r)*Cch + k0 + c8];
      *(u16x8*)&Bl[r][c8] = *(const u16x8*)&Blp[(size_t)(n0 + r)*Cch + k0 + c8];
    }
    __syncthreads();

    #pragma unroll
    for (int g2 = 0; g2 < 2; ++g2) {
      const int dof = g2*32 + 8*fg;
      bf16x8 aH[2], aL[2];
      #pragma unroll
      for (int qt = 0; qt < 2; ++qt) {
        aH[qt] = *(const bf16x8*)&Ah[wq + qt*16 + fr][dof];
        aL[qt] = *(const bf16x8*)&Al[wq + qt*16 + fr][dof];
      }
      #pragma unroll
      for (int kt = 0; kt < 4; ++kt) {
        const bf16x8 bH = *(const bf16x8*)&Bh[wk + kt*16 + fr][dof];
        const bf16x8 bL = *(const bf16x8*)&Bl[wk + kt*16 + fr][dof];
        #pragma unroll
        for (int qt = 0; qt < 2; ++qt) {
          acc[qt][kt] = __builtin_amdgcn_mfma_f32_16x16x32_bf16(
              aH[qt], bH, acc[qt][kt], 0, 0, 0);
          acc[qt][kt] = __builtin_amdgcn_mfma_f32_16x16x32_bf16(
              aH[qt], bL, acc[qt][kt], 0, 0, 0);
          acc[qt][kt] = __builtin_amdgcn_mfma_f32_16x16x32_bf16(
              aL[qt], bH, acc[qt][kt], 0, 0, 0);
        }
      }
    }
  }

  float bcol[4];
  #pragma unroll
  for (int kt = 0; kt < 4; ++kt) bcol[kt] = bias[n0 + wk + kt*16 + fr];

  unsigned short* __restrict__ dh = (z == 0) ? qh : kh;
  unsigned short* __restrict__ dl = (z == 0) ? ql : kl;

  #pragma unroll
  for (int qt = 0; qt < 2; ++qt) {
    #pragma unroll
    for (int j = 0; j < 4; ++j) {
      const int m  = m0 + wq + qt*16 + 4*fg + j;
      const int b  = m >> 10, tt = m & 1023;
      #pragma unroll
      for (int kt = 0; kt < 4; ++kt) {
        const int col = n0 + wk + kt*16 + fr;
        const float val = acc[qt][kt][j] + bcol[kt];
        const size_t idx =
            (((size_t)(b*Hc + (col >> 6)))*Tc + tt)*Dc + (col & 63);
        if (z < 2) {
          const unsigned short hb = bf16rne(val);
          dh[idx] = hb;
          dl[idx] = bf16rne(val - bf16tof(hb));
        } else {
          V[idx] = val;
        }
      }
    }
  }
}

// ---------------------------------------------------------------------------
// score_mfma: scores = 0.125 * Q @ K^T, split-bf16 MFMA.  (round-9 proven)
// ---------------------------------------------------------------------------
__global__ __launch_bounds__(256) void score_mfma(
    const unsigned short* __restrict__ qhp, const unsigned short* __restrict__ qlp,
    const unsigned short* __restrict__ khp, const unsigned short* __restrict__ klp,
    float* __restrict__ scores)
{
  const int k0 = blockIdx.x * 128;
  const int q0 = blockIdx.y * 64;
  const int bh = blockIdx.z;

  __shared__ unsigned short Qh[64][72],  Ql[64][72];
  __shared__ unsigned short Kh[128][72], Kl[128][72];

  const int t = threadIdx.x;
  const size_t qb = ((size_t)bh*Tc + q0) * Dc;
  const size_t kb = ((size_t)bh*Tc + k0) * Dc;

  #pragma unroll
  for (int i = 0; i < 2; ++i) {
    const int id = t + 256*i;
    const int r = id >> 3, c8 = (id & 7) * 8;
    *(u16x8*)&Qh[r][c8] = *(const u16x8*)&qhp[qb + (size_t)r*Dc + c8];
    *(u16x8*)&Ql[r][c8] = *(const u16x8*)&qlp[qb + (size_t)r*Dc + c8];
  }
  #pragma unroll
  for (int i = 0; i < 4; ++i) {
    const int id = t + 256*i;
    const int r = id >> 3, c8 = (id & 7) * 8;
    *(u16x8*)&Kh[r][c8] = *(const u16x8*)&khp[kb + (size_t)r*Dc + c8];
    *(u16x8*)&Kl[r][c8] = *(const u16x8*)&klp[kb + (size_t)r*Dc + c8];
  }
  __syncthreads();

  const int lane = t & 63;
  const int wv   = t >> 6;
  const int wq   = (wv >> 1) * 32;
  const int wk   = (wv & 1) * 64;
  const int fr   = lane & 15;
  const int fg   = lane >> 4;

  f32x4 acc[2][4] = {};

  #pragma unroll
  for (int g2 = 0; g2 < 2; ++g2) {
    const int dof = g2*32 + 8*fg;
    bf16x8 aH[2], aL[2];
    #pragma unroll
    for (int qt = 0; qt < 2; ++qt) {
      aH[qt] = *(const bf16x8*)&Qh[wq + qt*16 + fr][dof];
      aL[qt] = *(const bf16x8*)&Ql[wq + qt*16 + fr][dof];
    }
    #pragma unroll
    for (int kt = 0; kt < 4; ++kt) {
      const bf16x8 bH = *(const bf16x8*)&Kh[wk + kt*16 + fr][dof];
      const bf16x8 bL = *(const bf16x8*)&Kl[wk + kt*16 + fr][dof];
      #pragma unroll
      for (int qt = 0; qt < 2; ++qt) {
        acc[qt][kt] = __builtin_amdgcn_mfma_f32_16x16x32_bf16(
            aH[qt], bH, acc[qt][kt], 0, 0, 0);
        acc[qt][kt] = __builtin_amdgcn_mfma_f32_16x16x32_bf16(
            aH[qt], bL, acc[qt][kt], 0, 0, 0);
        acc[qt][kt] = __builtin_amdgcn_mfma_f32_16x16x32_bf16(
            aL[qt], bH, acc[qt][kt], 0, 0, 0);
      }
    }
  }

  #pragma unroll
  for (int qt = 0; qt < 2; ++qt) {
    #pragma unroll
    for (int j = 0; j < 4; ++j) {
      const int qrow = q0 + wq + qt*16 + 4*fg + j;
      const size_t rb = ((size_t)bh * Tc + qrow) * Tc + k0 + wk;
      #pragma unroll
      for (int kt = 0; kt < 4; ++kt)
        scores[rb + kt*16 + fr] = acc[qt][kt][j] * 0.125f;
    }
  }
}

// ---------------------------------------------------------------------------
// ucb_topk: softmax + UCB top-k + renorm + count + sparse PV.
// A/B test round 12: TWO rows per wave (ILP on the shfl chains) with the
// ROUND-9 u64 key format ((u_bits<<32)|~idx -> single u64 max, tie-break
// baked in).  Isolates round 11's key-format change from its row change.
// ---------------------------------------------------------------------------
__global__ __launch_bounds__(256, 2) void ucb_topk(
    const float* __restrict__ qkv,
    const float* __restrict__ count_in,
    const int*   __restrict__ counter_p,
    const int*   __restrict__ ucb_p,
    float* __restrict__ probs,          // in: scaled scores; out: probs
    float* __restrict__ count_out,
    float* __restrict__ ctx)
{
  const int bh   = blockIdx.y;
  const int lane = threadIdx.x & 63;
  const int wv   = threadIdx.x >> 6;        // 0..3
  const int rowA = blockIdx.x * 8 + wv * 2;
  const int rowB = rowA + 1;
  const int b = bh / Hc, h = bh % Hc;
  const size_t rbA = ((size_t)bh * Tc + rowA) * Tc;
  const size_t rbB = ((size_t)bh * Tc + rowB) * Tc;
  const float* __restrict__ Vh = qkv + 2*BTC + (size_t)bh * Tc * Dc;

  __shared__ float psel[8][KSEL];     // winner s values, per row-in-block

  const int  counter = counter_p[0];
  const int  ucbf    = ucb_p[0];
  const bool do_ucb  = (ucbf != 0) && (counter >= 1000);
  const float lt     = do_ucb ? logf((float)counter) : 0.f;

  float sA[16], sB[16];
  #pragma unroll
  for (int w = 0; w < 16; ++w) sA[w] = probs[rbA + lane + 64*w];
  #pragma unroll
  for (int w = 0; w < 16; ++w) sB[w] = probs[rbB + lane + 64*w];

  // softmax, both rows interleaved
  float mxA = -INFINITY, mxB = -INFINITY;
  #pragma unroll
  for (int w = 0; w < 16; ++w) { mxA = fmaxf(mxA, sA[w]); mxB = fmaxf(mxB, sB[w]); }
  #pragma unroll
  for (int off = 32; off > 0; off >>= 1) {
    mxA = fmaxf(mxA, __shfl_xor(mxA, off));
    mxB = fmaxf(mxB, __shfl_xor(mxB, off));
  }
  float smA = 0.f, smB = 0.f;
  #pragma unroll
  for (int w = 0; w < 16; ++w) {
    sA[w] = __expf(sA[w] - mxA); smA += sA[w];
    sB[w] = __expf(sB[w] - mxB); smB += sB[w];
  }
  #pragma unroll
  for (int off = 32; off > 0; off >>= 1) {
    smA += __shfl_xor(smA, off);
    smB += __shfl_xor(smB, off);
  }
  const float rsA = 1.0f / smA, rsB = 1.0f / smB;
  #pragma unroll
  for (int w = 0; w < 16; ++w) { sA[w] *= rsA; sB[w] *= rsB; }   // att

  if (do_ucb) {
    const float sqlt = sqrtf(lt);

    // u64 keys (round-9 format): (u_bits << 32) | ~idx  -- u > 0 always, so
    // bit order == value order; ~idx gives lowest-index tie-break for free.
    unsigned long long keyA[16], keyB[16];
    #pragma unroll
    for (int w = 0; w < 16; ++w) {
      const float cA = count_in[rbA + lane + 64*w];
      count_out[rbA + lane + 64*w] = cA;
      const float uA = fmaf(sqlt, rsqrtf(cA + 1e-8f), sA[w]);
      keyA[w] = ((unsigned long long)__float_as_uint(uA) << 32)
              | (unsigned long long)(~(unsigned)(lane + (w << 6)));
      const float cB = count_in[rbB + lane + 64*w];
      count_out[rbB + lane + 64*w] = cB;
      const float uB = fmaf(sqlt, rsqrtf(cB + 1e-8f), sB[w]);
      keyB[w] = ((unsigned long long)__float_as_uint(uB) << 32)
              | (unsigned long long)(~(unsigned)(lane + (w << 6)));
    }

    unsigned selA = 0u, selB = 0u;
    unsigned long long rpA = 0ull, rpB = 0ull;   // 4-bit round id per w slot
    int ksA[KSEL], ksB[KSEL];                    // wave-uniform (SGPR)

    #pragma unroll
    for (int r = 0; r < KSEL; ++r) {
      // lane-local max over unselected (zero-under-mask; valid keys nonzero)
      unsigned long long mA = 0ull, mB = 0ull;
      #pragma unroll
      for (int w = 0; w < 16; ++w) {
        const unsigned long long kwA = ((selA >> w) & 1u) ? 0ull : keyA[w];
        mA = (kwA > mA) ? kwA : mA;
        const unsigned long long kwB = ((selB >> w) & 1u) ? 0ull : keyB[w];
        mB = (kwB > mB) ? kwB : mB;
      }
      // butterfly max, A/B chains interleaved (independent -> ILP)
      #pragma unroll
      for (int off = 32; off > 0; off >>= 1) {
        const unsigned long long oA = __shfl_xor(mA, off);
        const unsigned long long oB = __shfl_xor(mB, off);
        mA = (oA > mA) ? oA : mA;
        mB = (oB > mB) ? oB : mB;
      }
      const int idxA = (int)(~(unsigned)(mA & 0xFFFFFFFFull));
      const int idxB = (int)(~(unsigned)(mB & 0xFFFFFFFFull));
      ksA[r] = __builtin_amdgcn_readfirstlane(idxA);
      ksB[r] = __builtin_amdgcn_readfirstlane(idxB);
      if ((idxA & 63) == lane) {
        const int wsel = idxA >> 6;
        selA |= 1u << wsel;
        rpA  |= ((unsigned long long)r) << (4 * wsel);
      }
      if ((idxB & 63) == lane) {
        const int wsel = idxB >> 6;
        selB |= 1u << wsel;
        rpB  |= ((unsigned long long)r) << (4 * wsel);
      }
    }

    // publish winner s values (owner lanes) to LDS, keyed by round id
    #pragma unroll
    for (int w = 0; w < 16; ++w) {
      if ((selA >> w) & 1u)
        psel[2*wv    ][(int)((rpA >> (4 * w)) & 15ull)] = sA[w];
      if ((selB >> w) & 1u)
        psel[2*wv + 1][(int)((rpB >> (4 * w)) & 15ull)] = sB[w];
    }
    __syncthreads();    // do_ucb is grid-uniform; all waves reach this

    float pvvA[KSEL], pvvB[KSEL];
    float denA = 1e-8f, denB = 1e-8f;
    #pragma unroll
    for (int r = 0; r < KSEL; ++r) {
      pvvA[r] = psel[2*wv][r];     denA += pvvA[r];
      pvvB[r] = psel[2*wv + 1][r]; denB += pvvB[r];
    }
    const float rdA = 1.0f / denA, rdB = 1.0f / denB;

    #pragma unroll
    for (int w = 0; w < 16; ++w) {
      probs[rbA + lane + 64*w] = ((selA >> w) & 1u) ? (sA[w] * rdA) : 0.0f;
      probs[rbB + lane + 64*w] = ((selB >> w) & 1u) ? (sB[w] * rdB) : 0.0f;
    }
    #pragma unroll
    for (int r = 0; r < KSEL; ++r) {
      if ((ksA[r] & 63) == lane)
        count_out[rbA + ksA[r]] = count_in[rbA + ksA[r]] + 1.0f;
      if ((ksB[r] & 63) == lane)
        count_out[rbB + ksB[r]] = count_in[rbB + ksB[r]] + 1.0f;
    }

    float cdA = 0.f, cdB = 0.f;
    #pragma unroll
    for (int r = 0; r < KSEL; ++r) {
      cdA += pvvA[r] * Vh[(size_t)ksA[r] * Dc + lane];
      cdB += pvvB[r] * Vh[(size_t)ksB[r] * Dc + lane];
    }
    ctx[((size_t)b*Tc + rowA)*Cch + h*Dc + lane] = cdA * rdA;
    ctx[((size_t)b*Tc + rowB)*Cch + h*Dc + lane] = cdB * rdB;
  } else {
    #pragma unroll
    for (int w = 0; w < 16; ++w) {
      probs[rbA + lane + 64*w]     = sA[w];
      count_out[rbA + lane + 64*w] = count_in[rbA + lane + 64*w];
      probs[rbB + lane + 64*w]     = sB[w];
      count_out[rbB + lane + 64*w] = count_in[rbB + lane + 64*w];
    }
  }
}

// ---------------------------------------------------------------------------
// K3 (fallback only, non-UCB path): ctx = probs @ V per (b,h).
// ---------------------------------------------------------------------------
__global__ __launch_bounds__(256) void pv_gemm(
    const float* __restrict__ probs,
    const float* __restrict__ Vm,
    float* __restrict__ ctx,
    const int* __restrict__ counter_p,
    const int* __restrict__ ucb_p)
{
  if ((ucb_p[0] != 0) && (counter_p[0] >= 1000)) return;  // topk did sparse PV

  const int bh = blockIdx.y;
  const int q0 = blockIdx.x * 64;
  const int b = bh / Hc, h = bh % Hc;

  __shared__ float aT[32][68];
  __shared__ float vN[32][68];

  const int t  = threadIdx.x;
  const int tn = t & 15;
  const int tq = t >> 4;

  float acc[4][4];
  #pragma unroll
  for (int i = 0; i < 4; ++i)
    #pragma unroll
    for (int j = 0; j < 4; ++j) acc[i][j] = 0.f;

  for (int k0 = 0; k0 < Tc; k0 += 32) {
    __syncthreads();
    #pragma unroll
    for (int p = 0; p < 2; ++p) {
      const int id = t + 256*p;
      const int r = id >> 3, c = id & 7;
      const float4 v =
          *(const float4*)&probs[((size_t)bh*Tc + q0 + r)*Tc + k0 + 4*c];
      aT[4*c + 0][r] = v.x; aT[4*c + 1][r] = v.y;
      aT[4*c + 2][r] = v.z; aT[4*c + 3][r] = v.w;
    }
    #pragma unroll
    for (int p = 0; p < 2; ++p) {
      const int id = t + 256*p;
      const int kk = id >> 4, dcc = id & 15;
      const float4 v = *(const float4*)&Vm[((size_t)bh*Tc + k0 + kk)*Dc + 4*dcc];
      *(float4*)&vN[kk][4*dcc] = v;
    }
    __syncthreads();
    #pragma unroll
    for (int kk = 0; kk < 32; ++kk) {
      const float4 a  = *(const float4*)&aT[kk][4*tq];
      const float4 vv = *(const float4*)&vN[kk][4*tn];
      const float av[4] = {a.x, a.y, a.z, a.w};
      const float bw[4] = {vv.x, vv.y, vv.z, vv.w};
      #pragma unroll
      for (int qi = 0; qi < 4; ++qi)
        #pragma unroll
        for (int ni = 0; ni < 4; ++ni) acc[qi][ni] += av[qi] * bw[ni];
    }
  }

  #pragma unroll
  for (int qi = 0; qi < 4; ++qi) {
    const int tt = q0 + 4*tq + qi;
    float4 o;
    o.x = acc[qi][0]; o.y = acc[qi][1]; o.z = acc[qi][2]; o.w = acc[qi][3];
    *(float4*)&ctx[((size_t)b*Tc + tt)*Cch + h*Dc + 4*tn] = o;
  }
}

// ---------------------------------------------------------------------------
// out_mfma: out = ctx @ Wo + bo, split-bf16 MFMA.  (unchanged)
// ---------------------------------------------------------------------------
__global__ __launch_bounds__(256) void out_mfma(
    const unsigned short* __restrict__ ah, const unsigned short* __restrict__ al,
    const unsigned short* __restrict__ bth, const unsigned short* __restrict__ btl,
    const float* __restrict__ bias,
    float* __restrict__ out)
{
  const int m0 = blockIdx.y * 64;
  const int n0 = blockIdx.x * 128;

  __shared__ unsigned short Ah[64][72],  Al[64][72];
  __shared__ unsigned short Bh[128][72], Bl[128][72];

  const int t    = threadIdx.x;
  const int lane = t & 63;
  const int wv   = t >> 6;
  const int wq   = (wv >> 1) * 32;
  const int wk   = (wv & 1) * 64;
  const int fr   = lane & 15;
  const int fg   = lane >> 4;

  f32x4 acc[2][4] = {};

  for (int k0 = 0; k0 < Cch; k0 += 64) {
    __syncthreads();
    #pragma unroll
    for (int i = 0; i < 2; ++i) {
      const int id = t + 256*i;
      const int r = id >> 3, c8 = (id & 7) * 8;
      *(u16x8*)&Ah[r][c8] = *(const u16x8*)&ah[(size_t)(m0 + r)*Cch + k0 + c8];
      *(u16x8*)&Al[r][c8] = *(const u16x8*)&al[(size_t)(m0 + r)*Cch + k0 + c8];
    }
    #pragma unroll
    for (int i = 0; i < 4; ++i) {
      const int id = t + 256*i;
      const int r = id >> 3, c8 = (id & 7) * 8;
      *(u16x8*)&Bh[r][c8] = *(const u16x8*)&bth[(size_t)(n0 + r)*Cch + k0 + c8];
      *(u16x8*)&Bl[r][c8] = *(const u16x8*)&btl[(size_t)(n0 + r)*Cch + k0 + c8];
    }
    __syncthreads();

    #pragma unroll
    for (int g2 = 0; g2 < 2; ++g2) {
      const int dof = g2*32 + 8*fg;
      bf16x8 aH[2], aL[2];
      #pragma unroll
      for (int qt = 0; qt < 2; ++qt) {
        aH[qt] = *(const bf16x8*)&Ah[wq + qt*16 + fr][dof];
        aL[qt] = *(const bf16x8*)&Al[wq + qt*16 + fr][dof];
      }
      #pragma unroll
      for (int kt = 0; kt < 4; ++kt) {
        const bf16x8 bH = *(const bf16x8*)&Bh[wk + kt*16 + fr][dof];
        const bf16x8 bL = *(const bf16x8*)&Bl[wk + kt*16 + fr][dof];
        #pragma unroll
        for (int qt = 0; qt < 2; ++qt) {
          acc[qt][kt] = __builtin_amdgcn_mfma_f32_16x16x32_bf16(
              aH[qt], bH, acc[qt][kt], 0, 0, 0);
          acc[qt][kt] = __builtin_amdgcn_mfma_f32_16x16x32_bf16(
              aH[qt], bL, acc[qt][kt], 0, 0, 0);
          acc[qt][kt] = __builtin_amdgcn_mfma_f32_16x16x32_bf16(
              aL[qt], bH, acc[qt][kt], 0, 0, 0);
        }
      }
    }
  }

  float bcol[4];
  #pragma unroll
  for (int kt = 0; kt < 4; ++kt) bcol[kt] = bias[n0 + wk + kt*16 + fr];

  #pragma unroll
  for (int qt = 0; qt < 2; ++qt) {
    #pragma unroll
    for (int j = 0; j < 4; ++j) {
      const int m = m0 + wq + qt*16 + 4*fg + j;
      #pragma unroll
      for (int kt = 0; kt < 4; ++kt) {
        const int col = n0 + wk + kt*16 + fr;
        out[(size_t)m * Cch + col] = acc[qt][kt][j] + bcol[kt];
      }
    }
  }
}

} // anonymous namespace

// ---------------------------------------------------------------------------
extern "C" void kernel_launch(void* const* d_in, const int* in_sizes, int n_in,
                              void* d_out, int out_size, void* d_ws, size_t ws_size,
                              hipStream_t stream) {
  (void)in_sizes; (void)n_in; (void)out_size; (void)ws_size;

  const float* hid  = (const float*)d_in[0];
  const float* cnt  = (const float*)d_in[1];
  const float* Wq   = (const float*)d_in[2];
  const float* bq   = (const float*)d_in[3];
  const float* Wk   = (const float*)d_in[4];
  const float* bk   = (const float*)d_in[5];
  const float* Wv   = (const float*)d_in[6];
  const float* bv   = (const float*)d_in[7];
  const float* Wo   = (const float*)d_in[8];
  const float* bo   = (const float*)d_in[9];
  const int* counter = (const int*)d_in[10];
  const int* ucb     = (const int*)d_in[11];

  float* out       = (float*)d_out;          // [B,T,C]
  float* probs     = out + BTC;              // [B,H,T,T] (scores, then probs)
  float* count_out = probs + PROBSN;         // [B,H,T,T]

  // workspace: Qbf16(hi|lo) | Kbf16(hi|lo) | V f32 | ctx f32 (4 x BTC f32)
  float* ws  = (float*)d_ws;
  float* V   = ws + 2*BTC;
  float* ctx = ws + 3*BTC;
  unsigned short* qkb = (unsigned short*)d_ws;
  unsigned short* qh = qkb;
  unsigned short* ql = qkb + BTC;
  unsigned short* kh = qkb + 2*BTC;
  unsigned short* kl = qkb + 3*BTC;

  // pre-convert scratch lives in the count_out region of d_out (dead until
  // ucb_topk writes it; all consumers run before ucb_topk).
  unsigned short* cvt  = (unsigned short*)count_out;
  unsigned short* hidh = cvt;
  unsigned short* hidl = cvt + BTC;
  unsigned short* wqth = cvt + 2*BTC;
  unsigned short* wqtl = wqth + CC;
  unsigned short* wkth = wqtl + CC;
  unsigned short* wktl = wkth + CC;
  unsigned short* wvth = wktl + CC;
  unsigned short* wvtl = wvth + CC;

  // post-topk converts reuse the then-dead Q/K bf16 regions.
  unsigned short* ctxh = qkb;
  unsigned short* ctxl = qkb + BTC;
  unsigned short* woth = qkb + 2*BTC;
  unsigned short* wotl = woth + CC;

  split_plane<<<BTC/1024, 256, 0, stream>>>(hid, hidh, hidl);
  splitT_w<<<dim3(24, 24), 256, 0, stream>>>(Wq, wqth, wqtl);
  splitT_w<<<dim3(24, 24), 256, 0, stream>>>(Wk, wkth, wktl);
  splitT_w<<<dim3(24, 24), 256, 0, stream>>>(Wv, wvth, wvtl);

  qkv_mfma<<<dim3(Cch/128, (Bc*Tc)/64, 3), 256, 0, stream>>>(
      hidh, hidl, wqth, wqtl, wkth, wktl, wvth, wvtl,
      bq, bk, bv, qh, ql, kh, kl, V);

  score_mfma<<<dim3(Tc/128, Tc/64, Bc*Hc), 256, 0, stream>>>(
      qh, ql, kh, kl, probs);

  ucb_topk<<<dim3(Tc/8, Bc*Hc), 256, 0, stream>>>(
      ws, cnt, counter, ucb, probs, count_out, ctx);

  pv_gemm<<<dim3(Tc/64, Bc*Hc), 256, 0, stream>>>(
      probs, V, ctx, counter, ucb);

  split_plane<<<BTC/1024, 256, 0, stream>>>(ctx, ctxh, ctxl);
  splitT_w<<<dim3(24, 24), 256, 0, stream>>>(Wo, woth, wotl);

  out_mfma<<<dim3(Cch/128, (Bc*Tc)/64), 256, 0, stream>>>(
      ctxh, ctxl, woth, wotl, bo, out);
}

// Round 13
// 367.924 us; speedup vs baseline: 1.3464x; 1.1170x over previous
//
#include <hip/hip_runtime.h>
#include <math.h>

namespace {

constexpr int Bc = 4, Tc = 1024, Cch = 768, Hc = 12, Dc = 64, KSEL = 10;
constexpr size_t BTC    = (size_t)Bc * Tc * Cch;        // 3,145,728
constexpr size_t PROBSN = (size_t)Bc * Hc * Tc * Tc;    // 50,331,648
constexpr size_t CC     = (size_t)Cch * Cch;            // 589,824

typedef __attribute__((ext_vector_type(8))) short          bf16x8;
typedef __attribute__((ext_vector_type(4))) float          f32x4;
typedef __attribute__((ext_vector_type(4))) unsigned short u16x4;
typedef __attribute__((ext_vector_type(8))) unsigned short u16x8;

// round-to-nearest-even f32 -> bf16 (raw bits); finite inputs only
__device__ __forceinline__ unsigned short bf16rne(float x) {
  unsigned int u = __float_as_uint(x);
  return (unsigned short)((u + 0x7FFFu + ((u >> 16) & 1u)) >> 16);
}
__device__ __forceinline__ float bf16tof(unsigned short h) {
  return __uint_as_float(((unsigned int)h) << 16);
}

// ---------------------------------------------------------------------------
// DPP wave64 reductions (row_shr 1/2/4/8 + row_bcast 15/31 + readlane 63).
// VALU-latency cross-lane: no ds_bpermute on the dependency chain.
// ---------------------------------------------------------------------------
template <int CTRL, int RM, bool BC>
__device__ __forceinline__ float dppmovf(float x, float oldv) {
  return __int_as_float(__builtin_amdgcn_update_dpp(
      __float_as_int(oldv), __float_as_int(x), CTRL, RM, 0xf, BC));
}

__device__ __forceinline__ float wave_fmax(float x) {
  x = fmaxf(x, dppmovf<0x111, 0xf, false>(x, x));   // row_shr:1
  x = fmaxf(x, dppmovf<0x112, 0xf, false>(x, x));   // row_shr:2
  x = fmaxf(x, dppmovf<0x114, 0xf, false>(x, x));   // row_shr:4
  x = fmaxf(x, dppmovf<0x118, 0xf, false>(x, x));   // row_shr:8
  x = fmaxf(x, dppmovf<0x142, 0xa, false>(x, x));   // row_bcast:15
  x = fmaxf(x, dppmovf<0x143, 0xc, false>(x, x));   // row_bcast:31
  return __int_as_float(__builtin_amdgcn_readlane(__float_as_int(x), 63));
}

__device__ __forceinline__ float wave_fsum(float x) {
  x += dppmovf<0x111, 0xf, true>(x, 0.f);
  x += dppmovf<0x112, 0xf, true>(x, 0.f);
  x += dppmovf<0x114, 0xf, true>(x, 0.f);
  x += dppmovf<0x118, 0xf, true>(x, 0.f);
  x += dppmovf<0x142, 0xa, true>(x, 0.f);   // unwritten rows add old=0
  x += dppmovf<0x143, 0xc, true>(x, 0.f);
  return __int_as_float(__builtin_amdgcn_readlane(__float_as_int(x), 63));
}

template <int CTRL, int RM>
__device__ __forceinline__ unsigned long long dppmax64_step(unsigned long long k) {
  const int lo = (int)(unsigned)(k & 0xFFFFFFFFull);
  const int hi = (int)(unsigned)(k >> 32);
  const int lo2 = __builtin_amdgcn_update_dpp(lo, lo, CTRL, RM, 0xf, false);
  const int hi2 = __builtin_amdgcn_update_dpp(hi, hi, CTRL, RM, 0xf, false);
  const unsigned long long k2 =
      ((unsigned long long)(unsigned)hi2 << 32) | (unsigned)lo2;
  return (k2 > k) ? k2 : k;
}

__device__ __forceinline__ unsigned long long wave_kmax(unsigned long long k) {
  k = dppmax64_step<0x111, 0xf>(k);
  k = dppmax64_step<0x112, 0xf>(k);
  k = dppmax64_step<0x114, 0xf>(k);
  k = dppmax64_step<0x118, 0xf>(k);
  k = dppmax64_step<0x142, 0xa>(k);
  k = dppmax64_step<0x143, 0xc>(k);
  const int lo = __builtin_amdgcn_readlane((int)(unsigned)(k & 0xFFFFFFFFull), 63);
  const int hi = __builtin_amdgcn_readlane((int)(unsigned)(k >> 32), 63);
  return ((unsigned long long)(unsigned)hi << 32) | (unsigned)lo;
}

// ---------------------------------------------------------------------------
// split_plane: f32[n] -> bf16 hi/lo planes.  n multiple of 1024.
// ---------------------------------------------------------------------------
__global__ __launch_bounds__(256) void split_plane(
    const float* __restrict__ src,
    unsigned short* __restrict__ h, unsigned short* __restrict__ l)
{
  const size_t i = (size_t)(blockIdx.x * 256 + threadIdx.x) * 4;
  const float4 v = *(const float4*)&src[i];
  const float xs[4] = {v.x, v.y, v.z, v.w};
  u16x4 hh, ll;
  #pragma unroll
  for (int e = 0; e < 4; ++e) {
    const unsigned short hb = bf16rne(xs[e]);
    hh[e] = hb;
    ll[e] = bf16rne(xs[e] - bf16tof(hb));
  }
  *(u16x4*)&h[i] = hh;
  *(u16x4*)&l[i] = ll;
}

// ---------------------------------------------------------------------------
// splitT_w: W[k][n] (768x768 f32) -> transposed bf16 planes th/tl [n][k].
// ---------------------------------------------------------------------------
__global__ __launch_bounds__(256) void splitT_w(
    const float* __restrict__ W,
    unsigned short* __restrict__ th, unsigned short* __restrict__ tl)
{
  __shared__ float tile[32][33];
  const int n0 = blockIdx.x * 32, k0 = blockIdx.y * 32;
  const int x = threadIdx.x & 31, y = threadIdx.x >> 5;   // y 0..7

  #pragma unroll
  for (int i = 0; i < 4; ++i) {
    const int kk = y * 4 + i;
    tile[kk][x] = W[(size_t)(k0 + kk) * Cch + n0 + x];
  }
  __syncthreads();
  #pragma unroll
  for (int i = 0; i < 4; ++i) {
    const int nn = y * 4 + i;
    const float v = tile[x][nn];                          // = W[k0+x][n0+nn]
    const unsigned short hb = bf16rne(v);
    th[(size_t)(n0 + nn) * Cch + k0 + x] = hb;
    tl[(size_t)(n0 + nn) * Cch + k0 + x] = bf16rne(v - bf16tof(hb));
  }
}

// ---------------------------------------------------------------------------
// qkv_mfma: [Q|K|V] = hid @ W + b, split-bf16 MFMA.  (unchanged)
// ---------------------------------------------------------------------------
__global__ __launch_bounds__(256) void qkv_mfma(
    const unsigned short* __restrict__ hidh, const unsigned short* __restrict__ hidl,
    const unsigned short* __restrict__ wqth, const unsigned short* __restrict__ wqtl,
    const unsigned short* __restrict__ wkth, const unsigned short* __restrict__ wktl,
    const unsigned short* __restrict__ wvth, const unsigned short* __restrict__ wvtl,
    const float* __restrict__ bq, const float* __restrict__ bk,
    const float* __restrict__ bv,
    unsigned short* __restrict__ qh, unsigned short* __restrict__ ql,
    unsigned short* __restrict__ kh, unsigned short* __restrict__ kl,
    float* __restrict__ V)
{
  const int z = blockIdx.z;
  const unsigned short* __restrict__ Bhp = (z == 0) ? wqth : (z == 1) ? wkth : wvth;
  const unsigned short* __restrict__ Blp = (z == 0) ? wqtl : (z == 1) ? wktl : wvtl;
  const float* __restrict__ bias = (z == 0) ? bq : (z == 1) ? bk : bv;

  const int m0 = blockIdx.y * 64;
  const int n0 = blockIdx.x * 128;

  __shared__ unsigned short Ah[64][72],  Al[64][72];
  __shared__ unsigned short Bh[128][72], Bl[128][72];

  const int t    = threadIdx.x;
  const int lane = t & 63;
  const int wv   = t >> 6;
  const int wq   = (wv >> 1) * 32;
  const int wk   = (wv & 1) * 64;
  const int fr   = lane & 15;
  const int fg   = lane >> 4;

  f32x4 acc[2][4] = {};

  for (int k0 = 0; k0 < Cch; k0 += 64) {
    __syncthreads();
    #pragma unroll
    for (int i = 0; i < 2; ++i) {       // A: 64x64 x 2 planes
      const int id = t + 256*i;
      const int r = id >> 3, c8 = (id & 7) * 8;
      *(u16x8*)&Ah[r][c8] = *(const u16x8*)&hidh[(size_t)(m0 + r)*Cch + k0 + c8];
      *(u16x8*)&Al[r][c8] = *(const u16x8*)&hidl[(size_t)(m0 + r)*Cch + k0 + c8];
    }
    #pragma unroll
    for (int i = 0; i < 4; ++i) {       // B: 128x64 x 2 planes
      const int id = t + 256*i;
      const int r = id >> 3, c8 = (id & 7) * 8;
      *(u16x8*)&Bh[r][c8] = *(const u16x8*)&Bhp[(size_t)(n0 + r)*Cch + k0 + c8];
      *(u16x8*)&Bl[r][c8] = *(const u16x8*)&Blp[(size_t)(n0 + r)*Cch + k0 + c8];
    }
    __syncthreads();

    #pragma unroll
    for (int g2 = 0; g2 < 2; ++g2) {
      const int dof = g2*32 + 8*fg;
      bf16x8 aH[2], aL[2];
      #pragma unroll
      for (int qt = 0; qt < 2; ++qt) {
        aH[qt] = *(const bf16x8*)&Ah[wq + qt*16 + fr][dof];
        aL[qt] = *(const bf16x8*)&Al[wq + qt*16 + fr][dof];
      }
      #pragma unroll
      for (int kt = 0; kt < 4; ++kt) {
        const bf16x8 bH = *(const bf16x8*)&Bh[wk + kt*16 + fr][dof];
        const bf16x8 bL = *(const bf16x8*)&Bl[wk + kt*16 + fr][dof];
        #pragma unroll
        for (int qt = 0; qt < 2; ++qt) {
          acc[qt][kt] = __builtin_amdgcn_mfma_f32_16x16x32_bf16(
              aH[qt], bH, acc[qt][kt], 0, 0, 0);
          acc[qt][kt] = __builtin_amdgcn_mfma_f32_16x16x32_bf16(
              aH[qt], bL, acc[qt][kt], 0, 0, 0);
          acc[qt][kt] = __builtin_amdgcn_mfma_f32_16x16x32_bf16(
              aL[qt], bH, acc[qt][kt], 0, 0, 0);
        }
      }
    }
  }

  float bcol[4];
  #pragma unroll
  for (int kt = 0; kt < 4; ++kt) bcol[kt] = bias[n0 + wk + kt*16 + fr];

  unsigned short* __restrict__ dh = (z == 0) ? qh : kh;
  unsigned short* __restrict__ dl = (z == 0) ? ql : kl;

  #pragma unroll
  for (int qt = 0; qt < 2; ++qt) {
    #pragma unroll
    for (int j = 0; j < 4; ++j) {
      const int m  = m0 + wq + qt*16 + 4*fg + j;
      const int b  = m >> 10, tt = m & 1023;
      #pragma unroll
      for (int kt = 0; kt < 4; ++kt) {
        const int col = n0 + wk + kt*16 + fr;
        const float val = acc[qt][kt][j] + bcol[kt];
        const size_t idx =
            (((size_t)(b*Hc + (col >> 6)))*Tc + tt)*Dc + (col & 63);
        if (z < 2) {
          const unsigned short hb = bf16rne(val);
          dh[idx] = hb;
          dl[idx] = bf16rne(val - bf16tof(hb));
        } else {
          V[idx] = val;
        }
      }
    }
  }
}

// ---------------------------------------------------------------------------
// score_mfma: scores = 0.125 * Q @ K^T, split-bf16 MFMA.  (unchanged)
// ---------------------------------------------------------------------------
__global__ __launch_bounds__(256) void score_mfma(
    const unsigned short* __restrict__ qhp, const unsigned short* __restrict__ qlp,
    const unsigned short* __restrict__ khp, const unsigned short* __restrict__ klp,
    float* __restrict__ scores)
{
  const int k0 = blockIdx.x * 128;
  const int q0 = blockIdx.y * 64;
  const int bh = blockIdx.z;

  __shared__ unsigned short Qh[64][72],  Ql[64][72];
  __shared__ unsigned short Kh[128][72], Kl[128][72];

  const int t = threadIdx.x;
  const size_t qb = ((size_t)bh*Tc + q0) * Dc;
  const size_t kb = ((size_t)bh*Tc + k0) * Dc;

  #pragma unroll
  for (int i = 0; i < 2; ++i) {
    const int id = t + 256*i;
    const int r = id >> 3, c8 = (id & 7) * 8;
    *(u16x8*)&Qh[r][c8] = *(const u16x8*)&qhp[qb + (size_t)r*Dc + c8];
    *(u16x8*)&Ql[r][c8] = *(const u16x8*)&qlp[qb + (size_t)r*Dc + c8];
  }
  #pragma unroll
  for (int i = 0; i < 4; ++i) {
    const int id = t + 256*i;
    const int r = id >> 3, c8 = (id & 7) * 8;
    *(u16x8*)&Kh[r][c8] = *(const u16x8*)&khp[kb + (size_t)r*Dc + c8];
    *(u16x8*)&Kl[r][c8] = *(const u16x8*)&klp[kb + (size_t)r*Dc + c8];
  }
  __syncthreads();

  const int lane = t & 63;
  const int wv   = t >> 6;
  const int wq   = (wv >> 1) * 32;
  const int wk   = (wv & 1) * 64;
  const int fr   = lane & 15;
  const int fg   = lane >> 4;

  f32x4 acc[2][4] = {};

  #pragma unroll
  for (int g2 = 0; g2 < 2; ++g2) {
    const int dof = g2*32 + 8*fg;
    bf16x8 aH[2], aL[2];
    #pragma unroll
    for (int qt = 0; qt < 2; ++qt) {
      aH[qt] = *(const bf16x8*)&Qh[wq + qt*16 + fr][dof];
      aL[qt] = *(const bf16x8*)&Ql[wq + qt*16 + fr][dof];
    }
    #pragma unroll
    for (int kt = 0; kt < 4; ++kt) {
      const bf16x8 bH = *(const bf16x8*)&Kh[wk + kt*16 + fr][dof];
      const bf16x8 bL = *(const bf16x8*)&Kl[wk + kt*16 + fr][dof];
      #pragma unroll
      for (int qt = 0; qt < 2; ++qt) {
        acc[qt][kt] = __builtin_amdgcn_mfma_f32_16x16x32_bf16(
            aH[qt], bH, acc[qt][kt], 0, 0, 0);
        acc[qt][kt] = __builtin_amdgcn_mfma_f32_16x16x32_bf16(
            aH[qt], bL, acc[qt][kt], 0, 0, 0);
        acc[qt][kt] = __builtin_amdgcn_mfma_f32_16x16x32_bf16(
            aL[qt], bH, acc[qt][kt], 0, 0, 0);
      }
    }
  }

  #pragma unroll
  for (int qt = 0; qt < 2; ++qt) {
    #pragma unroll
    for (int j = 0; j < 4; ++j) {
      const int qrow = q0 + wq + qt*16 + 4*fg + j;
      const size_t rb = ((size_t)bh * Tc + qrow) * Tc + k0 + wk;
      #pragma unroll
      for (int kt = 0; kt < 4; ++kt)
        scores[rb + kt*16 + fr] = acc[qt][kt][j] * 0.125f;
    }
  }
}

// ---------------------------------------------------------------------------
// ucb_topk: softmax + UCB top-k + renorm + count + sparse PV.
// Round 13: 1 row/wave (round-9 structure, best measured) with ALL cross-lane
// reductions on DPP (row_shr/row_bcast + readlane63) instead of ds_bpermute
// butterflies -- the kernel was latency-bound on the shfl chains.
// u64 keys (u_bits<<32)|~idx keep the lowest-index tie-break baked in.
// ---------------------------------------------------------------------------
__global__ __launch_bounds__(256, 4) void ucb_topk(
    const float* __restrict__ qkv,
    const float* __restrict__ count_in,
    const int*   __restrict__ counter_p,
    const int*   __restrict__ ucb_p,
    float* __restrict__ probs,          // in: scaled scores; out: probs
    float* __restrict__ count_out,
    float* __restrict__ ctx)
{
  const int bh   = blockIdx.y;
  const int lane = threadIdx.x & 63;
  const int wv   = threadIdx.x >> 6;
  const int row  = blockIdx.x * 4 + wv;
  const int b = bh / Hc, h = bh % Hc;
  const size_t rb = ((size_t)bh * Tc + row) * Tc;
  const float* __restrict__ Vh = qkv + 2*BTC + (size_t)bh * Tc * Dc;

  __shared__ float psel[4][KSEL];     // winner s values, per row-in-block

  const int  counter = counter_p[0];
  const int  ucbf    = ucb_p[0];
  const bool do_ucb  = (ucbf != 0) && (counter >= 1000);
  const float lt     = do_ucb ? logf((float)counter) : 0.f;

  float s[16];
  #pragma unroll
  for (int w = 0; w < 16; ++w) s[w] = probs[rb + lane + 64*w];

  // softmax (scores already scaled by 0.125 in score_mfma) -- DPP reductions
  float mx = -INFINITY;
  #pragma unroll
  for (int w = 0; w < 16; ++w) mx = fmaxf(mx, s[w]);
  mx = wave_fmax(mx);

  float sum = 0.f;
  #pragma unroll
  for (int w = 0; w < 16; ++w) { s[w] = __expf(s[w] - mx); sum += s[w]; }
  sum = wave_fsum(sum);

  const float rsum = 1.0f / sum;
  #pragma unroll
  for (int w = 0; w < 16; ++w) s[w] = s[w] * rsum;     // att

  if (do_ucb) {
    const float sqlt = sqrtf(lt);

    // u64 keys; stream count through (bulk copy now, +1 fix-up later)
    unsigned long long key[16];
    #pragma unroll
    for (int w = 0; w < 16; ++w) {
      const float c = count_in[rb + lane + 64*w];
      count_out[rb + lane + 64*w] = c;
      const float u = fmaf(sqlt, rsqrtf(c + 1e-8f), s[w]);
      key[w] = ((unsigned long long)__float_as_uint(u) << 32)
             | (unsigned long long)(~(unsigned)(lane + (w << 6)));
    }

    unsigned selmask = 0u;
    unsigned long long rpack = 0ull;   // 4-bit round id per w slot
    int ks[KSEL];                      // wave-uniform selected indices

    #pragma unroll
    for (int r = 0; r < KSEL; ++r) {
      // lane-local max over unselected, 4-deep tree (all static indices)
      unsigned long long t0[8];
      #pragma unroll
      for (int w = 0; w < 8; ++w) {
        const unsigned long long a =
            ((selmask >> (2*w)) & 1u) ? 0ull : key[2*w];
        const unsigned long long bb =
            ((selmask >> (2*w + 1)) & 1u) ? 0ull : key[2*w + 1];
        t0[w] = (a > bb) ? a : bb;
      }
      unsigned long long t1[4];
      #pragma unroll
      for (int w = 0; w < 4; ++w)
        t1[w] = (t0[2*w] > t0[2*w+1]) ? t0[2*w] : t0[2*w+1];
      unsigned long long t2a = (t1[0] > t1[1]) ? t1[0] : t1[1];
      unsigned long long t2b = (t1[2] > t1[3]) ? t1[2] : t1[3];
      unsigned long long m   = (t2a > t2b) ? t2a : t2b;

      // wave max via DPP (no LDS-pipe ops); result uniform
      m = wave_kmax(m);

      const int idx = (int)(~(unsigned)(m & 0xFFFFFFFFull));
      ks[r] = idx;
      if ((idx & 63) == lane) {
        const int wsel = idx >> 6;
        selmask |= 1u << wsel;
        rpack   |= ((unsigned long long)r) << (4 * wsel);
      }
    }

    // publish winner s values (owner lanes) to LDS, keyed by round id
    #pragma unroll
    for (int w = 0; w < 16; ++w) {
      if ((selmask >> w) & 1u) {
        const int r = (int)((rpack >> (4 * w)) & 15ull);
        psel[wv][r] = s[w];
      }
    }
    __syncthreads();    // do_ucb is grid-uniform; all waves reach this

    float pvv[KSEL];
    float denom = 1e-8f;
    #pragma unroll
    for (int r = 0; r < KSEL; ++r) { pvv[r] = psel[wv][r]; denom += pvv[r]; }
    const float rden = 1.0f / denom;

    // probs write + count fix-up
    #pragma unroll
    for (int w = 0; w < 16; ++w) {
      const bool sb = (selmask >> w) & 1u;
      probs[rb + lane + 64*w] = sb ? (s[w] * rden) : 0.0f;
    }
    #pragma unroll
    for (int r = 0; r < KSEL; ++r) {
      if ((ks[r] & 63) == lane)
        count_out[rb + ks[r]] = count_in[rb + ks[r]] + 1.0f;
    }

    // sparse PV: ctx[d=lane] = (sum_r pvv[r] * V[ks[r]][d]) * rden
    float cd = 0.f;
    #pragma unroll
    for (int r = 0; r < KSEL; ++r)
      cd += pvv[r] * Vh[(size_t)ks[r] * Dc + lane];
    ctx[((size_t)b*Tc + row)*Cch + h*Dc + lane] = cd * rden;
  } else {
    #pragma unroll
    for (int w = 0; w < 16; ++w) {
      probs[rb + lane + 64*w]     = s[w];
      count_out[rb + lane + 64*w] = count_in[rb + lane + 64*w];
    }
  }
}

// ---------------------------------------------------------------------------
// K3 (fallback only, non-UCB path): ctx = probs @ V per (b,h).
// ---------------------------------------------------------------------------
__global__ __launch_bounds__(256) void pv_gemm(
    const float* __restrict__ probs,
    const float* __restrict__ Vm,
    float* __restrict__ ctx,
    const int* __restrict__ counter_p,
    const int* __restrict__ ucb_p)
{
  if ((ucb_p[0] != 0) && (counter_p[0] >= 1000)) return;  // topk did sparse PV

  const int bh = blockIdx.y;
  const int q0 = blockIdx.x * 64;
  const int b = bh / Hc, h = bh % Hc;

  __shared__ float aT[32][68];
  __shared__ float vN[32][68];

  const int t  = threadIdx.x;
  const int tn = t & 15;
  const int tq = t >> 4;

  float acc[4][4];
  #pragma unroll
  for (int i = 0; i < 4; ++i)
    #pragma unroll
    for (int j = 0; j < 4; ++j) acc[i][j] = 0.f;

  for (int k0 = 0; k0 < Tc; k0 += 32) {
    __syncthreads();
    #pragma unroll
    for (int p = 0; p < 2; ++p) {
      const int id = t + 256*p;
      const int r = id >> 3, c = id & 7;
      const float4 v =
          *(const float4*)&probs[((size_t)bh*Tc + q0 + r)*Tc + k0 + 4*c];
      aT[4*c + 0][r] = v.x; aT[4*c + 1][r] = v.y;
      aT[4*c + 2][r] = v.z; aT[4*c + 3][r] = v.w;
    }
    #pragma unroll
    for (int p = 0; p < 2; ++p) {
      const int id = t + 256*p;
      const int kk = id >> 4, dcc = id & 15;
      const float4 v = *(const float4*)&Vm[((size_t)bh*Tc + k0 + kk)*Dc + 4*dcc];
      *(float4*)&vN[kk][4*dcc] = v;
    }
    __syncthreads();
    #pragma unroll
    for (int kk = 0; kk < 32; ++kk) {
      const float4 a  = *(const float4*)&aT[kk][4*tq];
      const float4 vv = *(const float4*)&vN[kk][4*tn];
      const float av[4] = {a.x, a.y, a.z, a.w};
      const float bw[4] = {vv.x, vv.y, vv.z, vv.w};
      #pragma unroll
      for (int qi = 0; qi < 4; ++qi)
        #pragma unroll
        for (int ni = 0; ni < 4; ++ni) acc[qi][ni] += av[qi] * bw[ni];
    }
  }

  #pragma unroll
  for (int qi = 0; qi < 4; ++qi) {
    const int tt = q0 + 4*tq + qi;
    float4 o;
    o.x = acc[qi][0]; o.y = acc[qi][1]; o.z = acc[qi][2]; o.w = acc[qi][3];
    *(float4*)&ctx[((size_t)b*Tc + tt)*Cch + h*Dc + 4*tn] = o;
  }
}

// ---------------------------------------------------------------------------
// out_mfma: out = ctx @ Wo + bo, split-bf16 MFMA.  (unchanged)
// ---------------------------------------------------------------------------
__global__ __launch_bounds__(256) void out_mfma(
    const unsigned short* __restrict__ ah, const unsigned short* __restrict__ al,
    const unsigned short* __restrict__ bth, const unsigned short* __restrict__ btl,
    const float* __restrict__ bias,
    float* __restrict__ out)
{
  const int m0 = blockIdx.y * 64;
  const int n0 = blockIdx.x * 128;

  __shared__ unsigned short Ah[64][72],  Al[64][72];
  __shared__ unsigned short Bh[128][72], Bl[128][72];

  const int t    = threadIdx.x;
  const int lane = t & 63;
  const int wv   = t >> 6;
  const int wq   = (wv >> 1) * 32;
  const int wk   = (wv & 1) * 64;
  const int fr   = lane & 15;
  const int fg   = lane >> 4;

  f32x4 acc[2][4] = {};

  for (int k0 = 0; k0 < Cch; k0 += 64) {
    __syncthreads();
    #pragma unroll
    for (int i = 0; i < 2; ++i) {
      const int id = t + 256*i;
      const int r = id >> 3, c8 = (id & 7) * 8;
      *(u16x8*)&Ah[r][c8] = *(const u16x8*)&ah[(size_t)(m0 + r)*Cch + k0 + c8];
      *(u16x8*)&Al[r][c8] = *(const u16x8*)&al[(size_t)(m0 + r)*Cch + k0 + c8];
    }
    #pragma unroll
    for (int i = 0; i < 4; ++i) {
      const int id = t + 256*i;
      const int r = id >> 3, c8 = (id & 7) * 8;
      *(u16x8*)&Bh[r][c8] = *(const u16x8*)&bth[(size_t)(n0 + r)*Cch + k0 + c8];
      *(u16x8*)&Bl[r][c8] = *(const u16x8*)&btl[(size_t)(n0 + r)*Cch + k0 + c8];
    }
    __syncthreads();

    #pragma unroll
    for (int g2 = 0; g2 < 2; ++g2) {
      const int dof = g2*32 + 8*fg;
      bf16x8 aH[2], aL[2];
      #pragma unroll
      for (int qt = 0; qt < 2; ++qt) {
        aH[qt] = *(const bf16x8*)&Ah[wq + qt*16 + fr][dof];
        aL[qt] = *(const bf16x8*)&Al[wq + qt*16 + fr][dof];
      }
      #pragma unroll
      for (int kt = 0; kt < 4; ++kt) {
        const bf16x8 bH = *(const bf16x8*)&Bh[wk + kt*16 + fr][dof];
        const bf16x8 bL = *(const bf16x8*)&Bl[wk + kt*16 + fr][dof];
        #pragma unroll
        for (int qt = 0; qt < 2; ++qt) {
          acc[qt][kt] = __builtin_amdgcn_mfma_f32_16x16x32_bf16(
              aH[qt], bH, acc[qt][kt], 0, 0, 0);
          acc[qt][kt] = __builtin_amdgcn_mfma_f32_16x16x32_bf16(
              aH[qt], bL, acc[qt][kt], 0, 0, 0);
          acc[qt][kt] = __builtin_amdgcn_mfma_f32_16x16x32_bf16(
              aL[qt], bH, acc[qt][kt], 0, 0, 0);
        }
      }
    }
  }

  float bcol[4];
  #pragma unroll
  for (int kt = 0; kt < 4; ++kt) bcol[kt] = bias[n0 + wk + kt*16 + fr];

  #pragma unroll
  for (int qt = 0; qt < 2; ++qt) {
    #pragma unroll
    for (int j = 0; j < 4; ++j) {
      const int m = m0 + wq + qt*16 + 4*fg + j;
      #pragma unroll
      for (int kt = 0; kt < 4; ++kt) {
        const int col = n0 + wk + kt*16 + fr;
        out[(size_t)m * Cch + col] = acc[qt][kt][j] + bcol[kt];
      }
    }
  }
}

} // anonymous namespace

// ---------------------------------------------------------------------------
extern "C" void kernel_launch(void* const* d_in, const int* in_sizes, int n_in,
                              void* d_out, int out_size, void* d_ws, size_t ws_size,
                              hipStream_t stream) {
  (void)in_sizes; (void)n_in; (void)out_size; (void)ws_size;

  const float* hid  = (const float*)d_in[0];
  const float* cnt  = (const float*)d_in[1];
  const float* Wq   = (const float*)d_in[2];
  const float* bq   = (const float*)d_in[3];
  const float* Wk   = (const float*)d_in[4];
  const float* bk   = (const float*)d_in[5];
  const float* Wv   = (const float*)d_in[6];
  const float* bv   = (const float*)d_in[7];
  const float* Wo   = (const float*)d_in[8];
  const float* bo   = (const float*)d_in[9];
  const int* counter = (const int*)d_in[10];
  const int* ucb     = (const int*)d_in[11];

  float* out       = (float*)d_out;          // [B,T,C]
  float* probs     = out + BTC;              // [B,H,T,T] (scores, then probs)
  float* count_out = probs + PROBSN;         // [B,H,T,T]

  // workspace: Qbf16(hi|lo) | Kbf16(hi|lo) | V f32 | ctx f32 (4 x BTC f32)
  float* ws  = (float*)d_ws;
  float* V   = ws + 2*BTC;
  float* ctx = ws + 3*BTC;
  unsigned short* qkb = (unsigned short*)d_ws;
  unsigned short* qh = qkb;
  unsigned short* ql = qkb + BTC;
  unsigned short* kh = qkb + 2*BTC;
  unsigned short* kl = qkb + 3*BTC;

  // pre-convert scratch lives in the count_out region of d_out (dead until
  // ucb_topk writes it; all consumers run before ucb_topk).
  unsigned short* cvt  = (unsigned short*)count_out;
  unsigned short* hidh = cvt;
  unsigned short* hidl = cvt + BTC;
  unsigned short* wqth = cvt + 2*BTC;
  unsigned short* wqtl = wqth + CC;
  unsigned short* wkth = wqtl + CC;
  unsigned short* wktl = wkth + CC;
  unsigned short* wvth = wktl + CC;
  unsigned short* wvtl = wvth + CC;

  // post-topk converts reuse the then-dead Q/K bf16 regions.
  unsigned short* ctxh = qkb;
  unsigned short* ctxl = qkb + BTC;
  unsigned short* woth = qkb + 2*BTC;
  unsigned short* wotl = woth + CC;

  split_plane<<<BTC/1024, 256, 0, stream>>>(hid, hidh, hidl);
  splitT_w<<<dim3(24, 24), 256, 0, stream>>>(Wq, wqth, wqtl);
  splitT_w<<<dim3(24, 24), 256, 0, stream>>>(Wk, wkth, wktl);
  splitT_w<<<dim3(24, 24), 256, 0, stream>>>(Wv, wvth, wvtl);

  qkv_mfma<<<dim3(Cch/128, (Bc*Tc)/64, 3), 256, 0, stream>>>(
      hidh, hidl, wqth, wqtl, wkth, wktl, wvth, wvtl,
      bq, bk, bv, qh, ql, kh, kl, V);

  score_mfma<<<dim3(Tc/128, Tc/64, Bc*Hc), 256, 0, stream>>>(
      qh, ql, kh, kl, probs);

  ucb_topk<<<dim3(Tc/4, Bc*Hc), 256, 0, stream>>>(
      ws, cnt, counter, ucb, probs, count_out, ctx);

  pv_gemm<<<dim3(Tc/64, Bc*Hc), 256, 0, stream>>>(
      probs, V, ctx, counter, ucb);

  split_plane<<<BTC/1024, 256, 0, stream>>>(ctx, ctxh, ctxl);
  splitT_w<<<dim3(24, 24), 256, 0, stream>>>(Wo, woth, wotl);

  out_mfma<<<dim3(Cch/128, (Bc*Tc)/64), 256, 0, stream>>>(
      ctxh, ctxl, woth, wotl, bo, out);
}